// Round 8
// baseline (594.473 us; speedup 1.0000x reference)
//
#include <hip/hip_runtime.h>
#include <stdint.h>

typedef __bf16 bf16_t;
typedef __bf16 bf16x8 __attribute__((ext_vector_type(8)));
typedef __bf16 bf16x4 __attribute__((ext_vector_type(4)));
typedef float  f32x4  __attribute__((ext_vector_type(4)));

constexpr int cBS = 64, cP = 512, cD = 1024, cDWM = 1024, cH = 16, cHD = 64, cW = 128;
constexpr int cVTP = 672;           // padded p-extent of Vt (sp = p + 128, max used 656)
constexpr int cM = cBS * cP;        // 32768
constexpr float cSCALE = 0.125f;    // 1/sqrt(64)

__device__ __forceinline__ void gld_lds16(const void* g, void* l) {
#if __has_builtin(__builtin_amdgcn_global_load_lds)
  __builtin_amdgcn_global_load_lds(
      (__attribute__((address_space(1))) void*)g,
      (__attribute__((address_space(3))) void*)l, 16, 0, 0);
#else
  *(bf16x8*)l = *(const bf16x8*)g;
#endif
}

// ---------------------------------------------------------------------------
// fp32 -> bf16 conversion of X
__global__ void cvt_x_k(const float* __restrict__ X, bf16_t* __restrict__ Y, int n) {
  int i = (blockIdx.x * blockDim.x + threadIdx.x) * 4;
  if (i >= n) return;
  float4 v = *(const float4*)(X + i);
  bf16x4 o;
  o[0] = (bf16_t)v.x; o[1] = (bf16_t)v.y; o[2] = (bf16_t)v.z; o[3] = (bf16_t)v.w;
  *(bf16x4*)(Y + i) = o;
}

// transpose + convert the four 1024x1024 weights: W[k][n] fp32 -> Wt[n][k] bf16
__global__ void cvt_wt_k(const float* __restrict__ W0, const float* __restrict__ W1,
                         const float* __restrict__ W2, const float* __restrict__ W3,
                         bf16_t* __restrict__ T0, bf16_t* __restrict__ T1,
                         bf16_t* __restrict__ T2, bf16_t* __restrict__ T3) {
  __shared__ float tile[32][33];
  const float* Wsrc; bf16_t* Tdst;
  switch (blockIdx.z) {
    case 0: Wsrc = W0; Tdst = T0; break;
    case 1: Wsrc = W1; Tdst = T1; break;
    case 2: Wsrc = W2; Tdst = T2; break;
    default: Wsrc = W3; Tdst = T3; break;
  }
  const int n0 = blockIdx.x * 32, k0 = blockIdx.y * 32;
  const int c = threadIdx.x & 31, r8 = threadIdx.x >> 5;
#pragma unroll
  for (int q = 0; q < 4; ++q) {
    int row = r8 + q * 8;
    tile[row][c] = Wsrc[(size_t)(k0 + row) * 1024 + n0 + c];
  }
  __syncthreads();
#pragma unroll
  for (int q = 0; q < 4; ++q) {
    int row = r8 + q * 8;
    Tdst[(size_t)(n0 + row) * 1024 + k0 + c] = (bf16_t)tile[c][row];
  }
}

// r[b][t] = index of last reset at-or-before t (0 if none): parallel max-scan
__global__ void resets2_k(const int* __restrict__ mask, int* __restrict__ r) {
  __shared__ int sm[cP];
  const int b = blockIdx.x, t = threadIdx.x;
  sm[t] = mask[b * cP + t] ? t : 0;
  __syncthreads();
#pragma unroll
  for (int d = 1; d < cP; d <<= 1) {
    int u = (t >= d) ? sm[t - d] : 0;
    __syncthreads();
    if (u > sm[t]) sm[t] = u;
    __syncthreads();
  }
  r[b * cP + t] = sm[t];
}

// ---------------------------------------------------------------------------
// Fused QKV GEMM, OCCUPANCY-FIRST restructure: 256x128 tile, 8 waves of
// 64x64 output each (acc = 64 regs), BK=32, TRIPLE-buffered 72 KiB LDS,
// __launch_bounds__(512,4) -> total regs <= 128 -> 2 blocks/CU (4 waves/SIMD).
// Cross-block async overlap hides barriers/prologue/epilogue (m114 mechanism)
// -- the axis R0-R7 never moved (all schedule variants pinned ~255-267 us at
// 1 block/CU).
// C[M][3072] = A[M][1024] * Wt[3072][1024]^T.
// Seg 0 -> Q head-major [b][h][p][hd], 1 -> K head-major, 2 -> Vt [b][h][hd][sp].
//
// LDS: 3 buffers x 24 KiB: A region 16 KiB (256 rows x 32 k) + B region 8 KiB
// (128 rows x 32 k), both in FRAGMENT ORDER (subtile = 16 rows x 32 k = 1 KiB;
// element (row r, 16B k-chunk c) at subtile*1024 + (c*16+(r&15))*16) -> a
// wave's frag ds_read_b128 covers 1024 consecutive bytes: 0 bank conflicts
// (verified R2). global_load_lds dest stays linear (tid*16); the GLOBAL
// source is permuted to match (rule #21).
//
// Per phase j (buf = j%3): 4 A-frags + 4 B-frags ds_read (compiler-interleaved
// lgkm waits), stage tile j+2 -> buf (j+2)%3 (3 gld_lds: A lo/hi + B),
// setprio(1) 16 MFMA setprio(0), VM3, barrier.
// Drain algebra: end of phase j, outstanding = {stage j+1 (3), stage j+2 (3)};
// VM3 drains j+1 (read next phase, issued a full phase earlier), keeps j+2.
// Never 0 mid-loop. WAR: stage j+2 overwrites tile j-1's buffer, last read in
// phase j-1, separated by that phase's end barrier.
__global__ __launch_bounds__(512, 4)
void gemm_qkv8_k(const bf16_t* __restrict__ A, const bf16_t* __restrict__ Wt,
                 const float* __restrict__ bq, const float* __restrict__ bk,
                 const float* __restrict__ bvv,
                 bf16_t* __restrict__ Qh, bf16_t* __restrict__ Kh,
                 bf16_t* __restrict__ Vt) {
  __shared__ __align__(16) char LDS[73728];     // 3 x 24 KiB
  const int tid = threadIdx.x;
  const int wid = tid >> 6, ln = tid & 63;
  const int ln15 = ln & 15, g4 = ln >> 4;
  const int wr = wid >> 1, wc = wid & 1;   // wave -> (row quarter, col half)

  // XCD swizzle: per-XCD m-slice, n-fastest so the A-panel stays L2-resident
  const int g = blockIdx.x + 24 * blockIdx.y;   // [0, 3072)
  const int xcd = g & 7, s = g >> 3;            // s in [0, 384)
  const int nb = s % 24, mloc = s / 24;         // mloc in [0, 16)
  const int m0 = (xcd * 16 + mloc) * 256, n0 = nb * 128;

  const bf16_t* Ab = A + (size_t)m0 * 1024;
  const bf16_t* Bb = Wt + (size_t)n0 * 1024;

  // staging map (per 16 KiB A region; B region uses the same formula, 1 chunk):
  // chunk q -> subtile q>>6, row-in-subtile q&15, k-chunk (q>>4)&3
  // global element = ((q>>6)*16 + (q&15))*1024 + ((q>>4)&3)*8
  const int srow = (tid >> 6) * 16 + (tid & 15);    // 0..127
  const int kc = (tid >> 4) & 3;
  const size_t aoff = (size_t)srow * 1024 + (size_t)(kc * 8);
  char* const lbase = LDS + tid * 16;

  // frag read lane addressing: 1024 consecutive bytes per subtile
  const int lane16 = (g4 * 16 + ln15) * 16;
  const int abase = (wr * 4) * 1024 + lane16;            // + mi*1024, mi 0..3
  const int bbase = 16384 + (wc * 4) * 1024 + lane16;    // + nj*1024, nj 0..3

  f32x4 acc[4][4];
#pragma unroll
  for (int i = 0; i < 4; ++i)
#pragma unroll
    for (int j = 0; j < 4; ++j) acc[i][j] = {0.f, 0.f, 0.f, 0.f};

#define STAGE(buf, j) do {                                                    \
    const bf16_t* gA_ = Ab + (size_t)((j) * 32) + aoff;                       \
    const bf16_t* gB_ = Bb + (size_t)((j) * 32) + aoff;                       \
    char* lp_ = lbase + (buf) * 24576;                                        \
    gld_lds16(gA_, lp_);                                                      \
    gld_lds16(gA_ + (size_t)128 * 1024, lp_ + 8192);                          \
    gld_lds16(gB_, lp_ + 16384);                                              \
  } while (0)

#define NOSTAGE ((void)0)
#define VM3 asm volatile("s_waitcnt vmcnt(3)" ::: "memory")
#define VM0 asm volatile("s_waitcnt vmcnt(0)" ::: "memory")
#define NOVM ((void)0)

// One phase: 8 frag reads (B then A), stage, 16 MFMA (compiler lgkm waits),
// counted vmcnt, barrier.
#define PHASE(buf, STAGE_, VME) do {                                          \
    const char* Ar_ = LDS + (buf) * 24576 + abase;                            \
    const char* Br_ = LDS + (buf) * 24576 + bbase;                            \
    bf16x8 af_[4], bf_[4];                                                    \
    _Pragma("unroll")                                                         \
    for (int nj_ = 0; nj_ < 4; ++nj_)                                         \
      bf_[nj_] = *(const bf16x8*)(Br_ + nj_ * 1024);                          \
    _Pragma("unroll")                                                         \
    for (int mi_ = 0; mi_ < 4; ++mi_)                                         \
      af_[mi_] = *(const bf16x8*)(Ar_ + mi_ * 1024);                          \
    STAGE_;                                                                   \
    __builtin_amdgcn_s_setprio(1);                                            \
    _Pragma("unroll")                                                         \
    for (int mi_ = 0; mi_ < 4; ++mi_)                                         \
      _Pragma("unroll")                                                       \
      for (int nj_ = 0; nj_ < 4; ++nj_)                                       \
        acc[mi_][nj_] = __builtin_amdgcn_mfma_f32_16x16x32_bf16(              \
            af_[mi_], bf_[nj_], acc[mi_][nj_], 0, 0, 0);                      \
    __builtin_amdgcn_s_setprio(0);                                            \
    VME;                                                                      \
    __builtin_amdgcn_s_barrier();                                             \
    __builtin_amdgcn_sched_barrier(0);                                        \
  } while (0)

  // prologue: stage tiles 0,1 (6 loads); drain tile0's 3 (keep tile1's)
  STAGE(0, 0);
  STAGE(1, 1);
  VM3;
  __builtin_amdgcn_s_barrier();
  __builtin_amdgcn_sched_barrier(0);

  // 32 K-tiles: 30 pipelined phases + 2 tail phases
  for (int t = 0; t < 10; ++t) {
    const int j = 3 * t;
    PHASE(0, STAGE(2, j + 2), VM3);
    PHASE(1, STAGE(0, j + 3), VM3);
    PHASE(2, STAGE(1, j + 4), VM3);
  }
  PHASE(0, NOSTAGE, VM0);   // tile 30; drain tile 31's loads
  PHASE(1, NOSTAGE, NOVM);  // tile 31

#undef PHASE
#undef STAGE

  const int seg = n0 >> 10;                      // block-uniform: 0=Q 1=K 2=V
  const float* bias = (seg == 0) ? bq : (seg == 1) ? bk : bvv;
  bf16_t* QK = (seg == 0) ? Qh : Kh;
#pragma unroll
  for (int mi = 0; mi < 4; ++mi) {
    const int rbase = m0 + wr * 64 + mi * 16 + g4 * 4;
    const int b = rbase >> 9, pb = rbase & 511;
#pragma unroll
    for (int nj = 0; nj < 4; ++nj) {
      const int col = n0 + wc * 64 + nj * 16 + ln15;
      const int cl = col & 1023;
      const int h = cl >> 6, hd = cl & 63;
      const float bv = bias[cl];
      if (seg < 2) {
        // head-major: [b][h][p][hd]
#pragma unroll
        for (int r = 0; r < 4; ++r)
          QK[(((size_t)(b * cH + h)) * cP + pb + r) * cHD + hd] =
              (bf16_t)(acc[mi][nj][r] + bv);
      } else {
        bf16x4 pk;
#pragma unroll
        for (int r = 0; r < 4; ++r) pk[r] = (bf16_t)(acc[mi][nj][r] + bv);
        *(bf16x4*)(Vt + ((size_t)((b * cH + h) * cHD + hd)) * cVTP + 128 + pb) = pk;
      }
    }
  }
}

// Output-projection GEMM (fp32 out), 128x128 tile + XCD swizzle
__global__ __launch_bounds__(256)
void gemm_bt_k(const bf16_t* __restrict__ A, const bf16_t* __restrict__ Bt,
               const float* __restrict__ bias, float* __restrict__ C,
               int M, int N, int K) {
  __shared__ __align__(16) bf16_t As[2][128 * 32];
  __shared__ __align__(16) bf16_t Bs[2][128 * 32];
  const int tid = threadIdx.x;
  const int wv = tid >> 6, ln = tid & 63;
  const int ln15 = ln & 15, g4 = ln >> 4;

  const int g = blockIdx.x + 8 * blockIdx.y;    // [0, 2048)
  const int xcd = g & 7, s = g >> 3;            // s in [0, 256)
  const int nb = s & 7, mloc = s >> 3;          // mloc in [0, 32)
  const int m0 = (xcd * 32 + mloc) * 128, n0 = nb * 128;

  const int wm = (wv >> 1) * 64, wn = (wv & 1) * 64;
  const bf16_t* Ab = A + (size_t)m0 * K;
  const bf16_t* Bb = Bt + (size_t)n0 * K;

  auto stage = [&](const bf16_t* G, bf16_t* L, int k0) {
#pragma unroll
    for (int gg = 0; gg < 2; ++gg) {
      int slot = gg * 256 + tid;
      gld_lds16(G + (size_t)(slot >> 2) * K + (k0 + (slot & 3) * 8), L + slot * 8);
    }
  };

  f32x4 acc[4][4];
#pragma unroll
  for (int i = 0; i < 4; ++i)
#pragma unroll
    for (int j = 0; j < 4; ++j) acc[i][j] = {0.f, 0.f, 0.f, 0.f};

  const int nk = K >> 5;
  stage(Ab, As[0], 0);
  stage(Bb, Bs[0], 0);
  for (int kt = 0; kt < nk; ++kt) {
    __syncthreads();
    if (kt + 1 < nk) {
      stage(Ab, As[(kt + 1) & 1], (kt + 1) * 32);
      stage(Bb, Bs[(kt + 1) & 1], (kt + 1) * 32);
    }
    const bf16_t* Asb = As[kt & 1];
    const bf16_t* Bsb = Bs[kt & 1];
    bf16x8 af[4], bfr[4];
#pragma unroll
    for (int i = 0; i < 4; ++i)
      af[i] = *(const bf16x8*)(Asb + (wm + i * 16 + ln15) * 32 + g4 * 8);
#pragma unroll
    for (int j = 0; j < 4; ++j)
      bfr[j] = *(const bf16x8*)(Bsb + (wn + j * 16 + ln15) * 32 + g4 * 8);
#pragma unroll
    for (int i = 0; i < 4; ++i)
#pragma unroll
      for (int j = 0; j < 4; ++j)
        acc[i][j] = __builtin_amdgcn_mfma_f32_16x16x32_bf16(af[i], bfr[j], acc[i][j], 0, 0, 0);
  }

#pragma unroll
  for (int i = 0; i < 4; ++i) {
    const int rbase = m0 + wm + i * 16 + g4 * 4;
#pragma unroll
    for (int j = 0; j < 4; ++j) {
      const int col = n0 + wn + j * 16 + ln15;
      const float bv = bias[col];
#pragma unroll
      for (int r = 0; r < 4; ++r)
        C[(size_t)(rbase + r) * N + col] = acc[i][j][r] + bv;
    }
  }
}

// ---------------------------------------------------------------------------
// Windowed attention v3: block = (head, batch, t-chunk); 4 waves each own a
// 16-token tile; 2 iterations cover the 128-token chunk. Q/K head-major.
__global__ __launch_bounds__(256)
void attn3_k(const bf16_t* __restrict__ Q, const bf16_t* __restrict__ Kv,
             const bf16_t* __restrict__ Vt, const int* __restrict__ rr,
             bf16_t* __restrict__ O) {
  __shared__ __align__(16) bf16_t Pl[4][16][168];
  const int tid = threadIdx.x;
  const int wv = tid >> 6, ln = tid & 63, ln15 = ln & 15, g4 = ln >> 4;
  const int h = blockIdx.x, b = blockIdx.y, tc = blockIdx.z;
  bf16_t(*Pw)[168] = Pl[wv];
  const bf16_t* vb = Vt + ((size_t)(b * cH + h)) * cHD * cVTP;
  const bf16_t* qb = Q + ((size_t)(b * cH + h)) * cP * cHD;
  const bf16_t* kb = Kv + ((size_t)(b * cH + h)) * cP * cHD;

  for (int sub = 0; sub < 2; ++sub) {
    const int t0 = (tc * 2 + sub) * 64 + wv * 16;
    const int sbase = t0 - 128;

    int rv[4];
#pragma unroll
    for (int r = 0; r < 4; ++r) rv[r] = rr[b * cP + t0 + g4 * 4 + r];

    // Q A-frag: m = ln15 (t), k = g4*8+j (hd)
    const bf16_t* qp = qb + (size_t)(t0 + ln15) * cHD + g4 * 8;
    const bf16x8 qa0 = *(const bf16x8*)qp;
    const bf16x8 qa1 = *(const bf16x8*)(qp + 32);

    // QK^T over 9 s-chunks of 16 (s in [t0-128, t0+15])
    f32x4 lg[9];
#pragma unroll
    for (int c = 0; c < 9; ++c) {
      const int s = sbase + c * 16 + ln15;  // B-frag n = ln15 (s), k = hd
      bf16x8 k0v, k1v;
      if ((unsigned)s < (unsigned)cP) {
        const bf16_t* kp = kb + (size_t)s * cHD + g4 * 8;
        k0v = *(const bf16x8*)kp;
        k1v = *(const bf16x8*)(kp + 32);
      } else {
#pragma unroll
        for (int z = 0; z < 8; ++z) { k0v[z] = (bf16_t)0.f; k1v[z] = (bf16_t)0.f; }
      }
      f32x4 a = {0.f, 0.f, 0.f, 0.f};
      a = __builtin_amdgcn_mfma_f32_16x16x32_bf16(qa0, k0v, a, 0, 0, 0);
      a = __builtin_amdgcn_mfma_f32_16x16x32_bf16(qa1, k1v, a, 0, 0, 0);
      lg[c] = a;
    }

    // mask + scale; C layout: col(s)=ln15, row(t)=g4*4+reg
    float mx[4] = {-1e30f, -1e30f, -1e30f, -1e30f};
#pragma unroll
    for (int c = 0; c < 9; ++c)
#pragma unroll
      for (int r = 0; r < 4; ++r) {
        const int s = sbase + c * 16 + ln15;
        const int t = t0 + g4 * 4 + r;
        const bool ok = (s >= rv[r]) && (s <= t) && (t - s < cW);
        const float l = ok ? lg[c][r] * cSCALE : -1e30f;
        lg[c][r] = l;
        mx[r] = fmaxf(mx[r], l);
      }
#pragma unroll
    for (int r = 0; r < 4; ++r) {
      mx[r] = fmaxf(mx[r], __shfl_xor(mx[r], 1));
      mx[r] = fmaxf(mx[r], __shfl_xor(mx[r], 2));
      mx[r] = fmaxf(mx[r], __shfl_xor(mx[r], 4));
      mx[r] = fmaxf(mx[r], __shfl_xor(mx[r], 8));
    }
    float sm[4] = {0.f, 0.f, 0.f, 0.f};
#pragma unroll
    for (int c = 0; c < 9; ++c)
#pragma unroll
      for (int r = 0; r < 4; ++r) {
        const float e = __expf(lg[c][r] - mx[r]);
        lg[c][r] = e;
        sm[r] += e;
      }
#pragma unroll
    for (int r = 0; r < 4; ++r) {
      sm[r] += __shfl_xor(sm[r], 1);
      sm[r] += __shfl_xor(sm[r], 2);
      sm[r] += __shfl_xor(sm[r], 4);
      sm[r] += __shfl_xor(sm[r], 8);
    }
    float inv[4];
#pragma unroll
    for (int r = 0; r < 4; ++r) inv[r] = 1.f / sm[r];

    // P -> LDS (C-layout write), zero pad cols 144..159 for the 5th PV chunk
#pragma unroll
    for (int c = 0; c < 9; ++c)
#pragma unroll
      for (int r = 0; r < 4; ++r)
        Pw[g4 * 4 + r][c * 16 + ln15] = (bf16_t)(lg[c][r] * inv[r]);
#pragma unroll
    for (int z = 0; z < 4; ++z)
      Pw[ln15][144 + g4 * 4 + z] = (bf16_t)0.f;

    // PV: A = P (m=t, k=s from LDS), B = Vt rows (n=hd, k=s contiguous)
    f32x4 oacc[4];
#pragma unroll
    for (int j = 0; j < 4; ++j) oacc[j] = {0.f, 0.f, 0.f, 0.f};
#pragma unroll
    for (int c2 = 0; c2 < 5; ++c2) {
      const bf16x8 pa = *(const bf16x8*)(&Pw[ln15][c2 * 32 + g4 * 8]);
#pragma unroll
      for (int j = 0; j < 4; ++j) {
        const bf16x8 vf =
            *(const bf16x8*)(vb + (size_t)(j * 16 + ln15) * cVTP + (t0 + c2 * 32 + g4 * 8));
        oacc[j] = __builtin_amdgcn_mfma_f32_16x16x32_bf16(pa, vf, oacc[j], 0, 0, 0);
      }
    }
#pragma unroll
    for (int j = 0; j < 4; ++j) {
      const int col = h * cHD + j * 16 + ln15;
#pragma unroll
      for (int r = 0; r < 4; ++r)
        O[((size_t)(b * cP + t0 + g4 * 4 + r)) * cDWM + col] = (bf16_t)oacc[j][r];
    }
  }
}

// ---------------------------------------------------------------------------
extern "C" void kernel_launch(void* const* d_in, const int* in_sizes, int n_in,
                              void* d_out, int out_size, void* d_ws, size_t ws_size,
                              hipStream_t stream) {
  (void)in_sizes; (void)n_in; (void)out_size; (void)ws_size;
  const float* x  = (const float*)d_in[0];
  const int* mask = (const int*)d_in[1];
  const float* Wq = (const float*)d_in[2];
  const float* bq = (const float*)d_in[3];
  const float* Wk = (const float*)d_in[4];
  const float* bk = (const float*)d_in[5];
  const float* Wv = (const float*)d_in[6];
  const float* bv = (const float*)d_in[7];
  const float* Wo = (const float*)d_in[8];
  const float* bo = (const float*)d_in[9];
  float* out = (float*)d_out;

  char* ws = (char*)d_ws;
  size_t off = 0;
  bf16_t* Xbf = (bf16_t*)(ws + off); off += (size_t)cM * cD * 2;          // 64 MiB
  bf16_t* Wqt = (bf16_t*)(ws + off); off += (size_t)cD * cDWM * 2;        // contiguous
  bf16_t* Wkt = (bf16_t*)(ws + off); off += (size_t)cD * cDWM * 2;        //   [3072][1024]
  bf16_t* Wvt = (bf16_t*)(ws + off); off += (size_t)cD * cDWM * 2;        //   QKV block
  bf16_t* Wot = (bf16_t*)(ws + off); off += (size_t)cDWM * cD * 2;
  bf16_t* Qh  = (bf16_t*)(ws + off); off += (size_t)cM * cDWM * 2;        // 64 MiB
  bf16_t* Kh  = (bf16_t*)(ws + off); off += (size_t)cM * cDWM * 2;        // 64 MiB
  bf16_t* Vt  = (bf16_t*)(ws + off); off += (size_t)cBS * cH * cHD * cVTP * 2;  // 84 MiB
  int* rbuf   = (int*)(ws + off);    off += (size_t)cBS * cP * 4;
  bf16_t* Ob  = Xbf;  // X no longer needed after the QKV projection

  cvt_x_k<<<(cM * cD / 4 + 255) / 256, 256, 0, stream>>>(x, Xbf, cM * cD);
  cvt_wt_k<<<dim3(32, 32, 4), 256, 0, stream>>>(Wq, Wk, Wv, Wo, Wqt, Wkt, Wvt, Wot);
  resets2_k<<<cBS, cP, 0, stream>>>(mask, rbuf);

  gemm_qkv8_k<<<dim3(24, 128), 512, 0, stream>>>(Xbf, Wqt, bq, bk, bv, Qh, Kh, Vt);

  attn3_k<<<dim3(cH, cBS, 4), 256, 0, stream>>>(Qh, Kh, Vt, rbuf, Ob);

  gemm_bt_k<<<dim3(8, 256), 256, 0, stream>>>(Ob, Wot, bo, out, cM, cD, cDWM);
}

// Round 9
// 521.267 us; speedup vs baseline: 1.1404x; 1.1404x over previous
//
#include <hip/hip_runtime.h>
#include <stdint.h>

typedef __bf16 bf16_t;
typedef __bf16 bf16x8 __attribute__((ext_vector_type(8)));
typedef __bf16 bf16x4 __attribute__((ext_vector_type(4)));
typedef float  f32x4  __attribute__((ext_vector_type(4)));

constexpr int cBS = 64, cP = 512, cD = 1024, cDWM = 1024, cH = 16, cHD = 64, cW = 128;
constexpr int cVTP = 672;           // padded p-extent of Vt (sp = p + 128, max used 656)
constexpr int cM = cBS * cP;        // 32768
constexpr float cSCALE = 0.125f;    // 1/sqrt(64)

__device__ __forceinline__ void gld_lds16(const void* g, void* l) {
#if __has_builtin(__builtin_amdgcn_global_load_lds)
  __builtin_amdgcn_global_load_lds(
      (__attribute__((address_space(1))) void*)g,
      (__attribute__((address_space(3))) void*)l, 16, 0, 0);
#else
  *(bf16x8*)l = *(const bf16x8*)g;
#endif
}

// ---------------------------------------------------------------------------
// fp32 -> bf16 conversion of X
__global__ void cvt_x_k(const float* __restrict__ X, bf16_t* __restrict__ Y, int n) {
  int i = (blockIdx.x * blockDim.x + threadIdx.x) * 4;
  if (i >= n) return;
  float4 v = *(const float4*)(X + i);
  bf16x4 o;
  o[0] = (bf16_t)v.x; o[1] = (bf16_t)v.y; o[2] = (bf16_t)v.z; o[3] = (bf16_t)v.w;
  *(bf16x4*)(Y + i) = o;
}

// transpose + convert the four 1024x1024 weights: W[k][n] fp32 -> Wt[n][k] bf16
__global__ void cvt_wt_k(const float* __restrict__ W0, const float* __restrict__ W1,
                         const float* __restrict__ W2, const float* __restrict__ W3,
                         bf16_t* __restrict__ T0, bf16_t* __restrict__ T1,
                         bf16_t* __restrict__ T2, bf16_t* __restrict__ T3) {
  __shared__ float tile[32][33];
  const float* Wsrc; bf16_t* Tdst;
  switch (blockIdx.z) {
    case 0: Wsrc = W0; Tdst = T0; break;
    case 1: Wsrc = W1; Tdst = T1; break;
    case 2: Wsrc = W2; Tdst = T2; break;
    default: Wsrc = W3; Tdst = T3; break;
  }
  const int n0 = blockIdx.x * 32, k0 = blockIdx.y * 32;
  const int c = threadIdx.x & 31, r8 = threadIdx.x >> 5;
#pragma unroll
  for (int q = 0; q < 4; ++q) {
    int row = r8 + q * 8;
    tile[row][c] = Wsrc[(size_t)(k0 + row) * 1024 + n0 + c];
  }
  __syncthreads();
#pragma unroll
  for (int q = 0; q < 4; ++q) {
    int row = r8 + q * 8;
    Tdst[(size_t)(n0 + row) * 1024 + k0 + c] = (bf16_t)tile[c][row];
  }
}

// r[b][t] = index of last reset at-or-before t (0 if none): parallel max-scan
__global__ void resets2_k(const int* __restrict__ mask, int* __restrict__ r) {
  __shared__ int sm[cP];
  const int b = blockIdx.x, t = threadIdx.x;
  sm[t] = mask[b * cP + t] ? t : 0;
  __syncthreads();
#pragma unroll
  for (int d = 1; d < cP; d <<= 1) {
    int u = (t >= d) ? sm[t - d] : 0;
    __syncthreads();
    if (u > sm[t]) sm[t] = u;
    __syncthreads();
  }
  r[b * cP + t] = sm[t];
}

// ---------------------------------------------------------------------------
// Fused QKV GEMM, 256x256 tile, 8-phase pipelined — EXACT Round-1 variant
// (fastest measured: 253 us, MfmaUtil 35).
// C[M][3072] = A[M][1024] * Wt[3072][1024]^T.
// Seg 0 -> Q head-major [b][h][p][hd], 1 -> K head-major, 2 -> Vt [b][h][hd][sp].
__global__ __launch_bounds__(512, 2)
void gemm_qkv8_k(const bf16_t* __restrict__ A, const bf16_t* __restrict__ Wt,
                 const float* __restrict__ bq, const float* __restrict__ bk,
                 const float* __restrict__ bvv,
                 bf16_t* __restrict__ Qh, bf16_t* __restrict__ Kh,
                 bf16_t* __restrict__ Vt) {
  __shared__ __align__(16) char LDS[131072];
  const int tid = threadIdx.x;
  const int wid = tid >> 6, ln = tid & 63;
  const int ln15 = ln & 15, g4 = ln >> 4;
  const int wr = wid >> 2, wc = wid & 3;   // wave -> (row half, col quarter)

  // XCD swizzle: per-XCD m-slice, n-fastest so the A-panel stays L2-resident
  const int g = blockIdx.x + 12 * blockIdx.y;   // [0, 1536)
  const int xcd = g & 7, s = g >> 3;            // s in [0, 192)
  const int nb = s % 12, mloc = s / 12;         // mloc in [0, 16)
  const int m0 = (xcd * 16 + mloc) * 256, n0 = nb * 256;

  const bf16_t* Ab = A + (size_t)m0 * 1024;
  const bf16_t* Bb = Wt + (size_t)n0 * 1024;

  // staging: thread covers 16B chunks q = i*512+tid; row=q>>2, phys slot=q&3,
  // logical slot = phys ^ (row&3) (involution) taken from the GLOBAL source.
  const int srow = tid >> 2;                        // 0..127 (i=1 adds 128)
  const int gslot = (tid & 3) ^ (srow & 3);
  const size_t aoff = (size_t)srow * 1024 + (size_t)(gslot * 8);
  char* const lbase = LDS + tid * 16;

  // ds_read lane addressing: row = <frag base> + ln15 (row&3 == ln15&3),
  // logical k-chunk g4 lives at phys slot g4 ^ (ln15&3).
  const int slotr = (g4 ^ (ln15 & 3)) << 4;
  const int abase = (wr * 128 + ln15) * 64 + slotr;          // + mi*1024
  const int bbase = 32768 + (wc * 64 + ln15) * 64 + slotr;   // + nj*1024

  f32x4 acc[8][4];
#pragma unroll
  for (int i = 0; i < 8; ++i)
#pragma unroll
    for (int j = 0; j < 4; ++j) acc[i][j] = {0.f, 0.f, 0.f, 0.f};

#define STAGE_A(buf, kh, j) do {                                              \
    const bf16_t* gp_ = Ab + (size_t)((j) * 64 + (kh) * 32) + aoff;           \
    char* lp_ = lbase + (buf) * 65536 + (kh) * 16384;                         \
    gld_lds16(gp_, lp_);                                                      \
    gld_lds16(gp_ + (size_t)128 * 1024, lp_ + 8192);                          \
  } while (0)

#define STAGE_B(buf, kh, j) do {                                              \
    const bf16_t* gp_ = Bb + (size_t)((j) * 64 + (kh) * 32) + aoff;           \
    char* lp_ = lbase + (buf) * 65536 + (kh) * 16384 + 32768;                 \
    gld_lds16(gp_, lp_);                                                      \
    gld_lds16(gp_ + (size_t)128 * 1024, lp_ + 8192);                          \
  } while (0)

#define NOSTAGE ((void)0)
#define VM4 asm volatile("s_waitcnt vmcnt(4)" ::: "memory")
#define VM0 asm volatile("s_waitcnt vmcnt(0)" ::: "memory")
#define NOVM ((void)0)

#define PHASE(buf, kh, qm, STAGE, VME) do {                                   \
    const char* Ar_ = LDS + (buf) * 65536 + (kh) * 16384 + abase + (qm) * 4096;\
    const char* Br_ = LDS + (buf) * 65536 + (kh) * 16384 + bbase;             \
    bf16x8 af_[4], bf_[4];                                                    \
    af_[0] = *(const bf16x8*)(Ar_);                                           \
    af_[1] = *(const bf16x8*)(Ar_ + 1024);                                    \
    af_[2] = *(const bf16x8*)(Ar_ + 2048);                                    \
    af_[3] = *(const bf16x8*)(Ar_ + 3072);                                    \
    bf_[0] = *(const bf16x8*)(Br_);                                           \
    bf_[1] = *(const bf16x8*)(Br_ + 1024);                                    \
    bf_[2] = *(const bf16x8*)(Br_ + 2048);                                    \
    bf_[3] = *(const bf16x8*)(Br_ + 3072);                                    \
    STAGE;                                                                    \
    __builtin_amdgcn_s_barrier();                                             \
    asm volatile("s_waitcnt lgkmcnt(0)" ::: "memory");                        \
    __builtin_amdgcn_s_setprio(1);                                            \
    _Pragma("unroll")                                                         \
    for (int mi4_ = 0; mi4_ < 4; ++mi4_)                                      \
      _Pragma("unroll")                                                       \
      for (int nj_ = 0; nj_ < 4; ++nj_)                                       \
        acc[(qm) * 4 + mi4_][nj_] = __builtin_amdgcn_mfma_f32_16x16x32_bf16(  \
            af_[mi4_], bf_[nj_], acc[(qm) * 4 + mi4_][nj_], 0, 0, 0);         \
    __builtin_amdgcn_s_setprio(0);                                            \
    VME;                                                                      \
    __builtin_amdgcn_s_barrier();                                             \
  } while (0)

  // prologue: tile0 (4 stages, 8 loads); drain its kh0 A+B (oldest 4 loads)
  STAGE_A(0, 0, 0); STAGE_B(0, 0, 0); STAGE_A(0, 1, 0); STAGE_B(0, 1, 0);
  asm volatile("s_waitcnt vmcnt(4)" ::: "memory");
  __builtin_amdgcn_s_barrier();

  for (int t = 0; t < 7; ++t) {
    const int j1 = 2 * t + 1, j2 = 2 * t + 2;
    PHASE(0, 0, 0, STAGE_A(1, 0, j1), NOVM);
    PHASE(0, 0, 1, STAGE_B(1, 0, j1), VM4);
    PHASE(0, 1, 0, STAGE_A(1, 1, j1), NOVM);
    PHASE(0, 1, 1, STAGE_B(1, 1, j1), VM4);
    PHASE(1, 0, 0, STAGE_A(0, 0, j2), NOVM);
    PHASE(1, 0, 1, STAGE_B(0, 0, j2), VM4);
    PHASE(1, 1, 0, STAGE_A(0, 1, j2), NOVM);
    PHASE(1, 1, 1, STAGE_B(0, 1, j2), VM4);
  }
  // tail: tiles 14,15; only tile15 still needs staging
  PHASE(0, 0, 0, STAGE_A(1, 0, 15), NOVM);
  PHASE(0, 0, 1, STAGE_B(1, 0, 15), VM4);
  PHASE(0, 1, 0, STAGE_A(1, 1, 15), NOVM);
  PHASE(0, 1, 1, STAGE_B(1, 1, 15), VM4);
  PHASE(1, 0, 0, NOSTAGE, NOVM);
  PHASE(1, 0, 1, NOSTAGE, VM0);
  PHASE(1, 1, 0, NOSTAGE, NOVM);
  PHASE(1, 1, 1, NOSTAGE, NOVM);

#undef PHASE
#undef STAGE_A
#undef STAGE_B

  const int seg = n0 >> 10;                      // block-uniform: 0=Q 1=K 2=V
  const float* bias = (seg == 0) ? bq : (seg == 1) ? bk : bvv;
  bf16_t* QK = (seg == 0) ? Qh : Kh;
#pragma unroll
  for (int mi = 0; mi < 8; ++mi) {
    const int rbase = m0 + wr * 128 + mi * 16 + g4 * 4;
    const int b = rbase >> 9, pb = rbase & 511;
#pragma unroll
    for (int nj = 0; nj < 4; ++nj) {
      const int col = n0 + wc * 64 + nj * 16 + ln15;
      const int cl = col & 1023;
      const int h = cl >> 6, hd = cl & 63;
      const float bv = bias[cl];
      if (seg < 2) {
        // head-major: [b][h][p][hd]
#pragma unroll
        for (int r = 0; r < 4; ++r)
          QK[(((size_t)(b * cH + h)) * cP + pb + r) * cHD + hd] =
              (bf16_t)(acc[mi][nj][r] + bv);
      } else {
        bf16x4 pk;
#pragma unroll
        for (int r = 0; r < 4; ++r) pk[r] = (bf16_t)(acc[mi][nj][r] + bv);
        *(bf16x4*)(Vt + ((size_t)((b * cH + h) * cHD + hd)) * cVTP + 128 + pb) = pk;
      }
    }
  }
}

// ---------------------------------------------------------------------------
// Output-projection GEMM: SAME verified 8-phase 256x256 structure as qkv
// (R0->R1 measured +18% vs 2-phase 128^2), fp32 output + bias epilogue.
// C[32768][1024] = Ob[32768][1024] * Wot[1024][1024]^T, grid 512 = 8x16x4.
__global__ __launch_bounds__(512, 2)
void gemm_bt8_k(const bf16_t* __restrict__ A, const bf16_t* __restrict__ Bt,
                const float* __restrict__ bias, float* __restrict__ C) {
  __shared__ __align__(16) char LDS[131072];
  const int tid = threadIdx.x;
  const int wid = tid >> 6, ln = tid & 63;
  const int ln15 = ln & 15, g4 = ln >> 4;
  const int wr = wid >> 2, wc = wid & 3;

  const int g = blockIdx.x + 4 * blockIdx.y;    // [0, 512)
  const int xcd = g & 7, s = g >> 3;            // s in [0, 64)
  const int nb = s & 3, mloc = s >> 2;          // mloc in [0, 16)
  const int m0 = (xcd * 16 + mloc) * 256, n0 = nb * 256;

  const bf16_t* Ab = A + (size_t)m0 * 1024;
  const bf16_t* Bb = Bt + (size_t)n0 * 1024;

  const int srow = tid >> 2;
  const int gslot = (tid & 3) ^ (srow & 3);
  const size_t aoff = (size_t)srow * 1024 + (size_t)(gslot * 8);
  char* const lbase = LDS + tid * 16;

  const int slotr = (g4 ^ (ln15 & 3)) << 4;
  const int abase = (wr * 128 + ln15) * 64 + slotr;
  const int bbase = 32768 + (wc * 64 + ln15) * 64 + slotr;

  f32x4 acc[8][4];
#pragma unroll
  for (int i = 0; i < 8; ++i)
#pragma unroll
    for (int j = 0; j < 4; ++j) acc[i][j] = {0.f, 0.f, 0.f, 0.f};

#define STAGE_A(buf, kh, j) do {                                              \
    const bf16_t* gp_ = Ab + (size_t)((j) * 64 + (kh) * 32) + aoff;           \
    char* lp_ = lbase + (buf) * 65536 + (kh) * 16384;                         \
    gld_lds16(gp_, lp_);                                                      \
    gld_lds16(gp_ + (size_t)128 * 1024, lp_ + 8192);                          \
  } while (0)

#define STAGE_B(buf, kh, j) do {                                              \
    const bf16_t* gp_ = Bb + (size_t)((j) * 64 + (kh) * 32) + aoff;           \
    char* lp_ = lbase + (buf) * 65536 + (kh) * 16384 + 32768;                 \
    gld_lds16(gp_, lp_);                                                      \
    gld_lds16(gp_ + (size_t)128 * 1024, lp_ + 8192);                          \
  } while (0)

#define NOSTAGE ((void)0)
#define VM4 asm volatile("s_waitcnt vmcnt(4)" ::: "memory")
#define VM0 asm volatile("s_waitcnt vmcnt(0)" ::: "memory")
#define NOVM ((void)0)

#define PHASE(buf, kh, qm, STAGE, VME) do {                                   \
    const char* Ar_ = LDS + (buf) * 65536 + (kh) * 16384 + abase + (qm) * 4096;\
    const char* Br_ = LDS + (buf) * 65536 + (kh) * 16384 + bbase;             \
    bf16x8 af_[4], bf_[4];                                                    \
    af_[0] = *(const bf16x8*)(Ar_);                                           \
    af_[1] = *(const bf16x8*)(Ar_ + 1024);                                    \
    af_[2] = *(const bf16x8*)(Ar_ + 2048);                                    \
    af_[3] = *(const bf16x8*)(Ar_ + 3072);                                    \
    bf_[0] = *(const bf16x8*)(Br_);                                           \
    bf_[1] = *(const bf16x8*)(Br_ + 1024);                                    \
    bf_[2] = *(const bf16x8*)(Br_ + 2048);                                    \
    bf_[3] = *(const bf16x8*)(Br_ + 3072);                                    \
    STAGE;                                                                    \
    __builtin_amdgcn_s_barrier();                                             \
    asm volatile("s_waitcnt lgkmcnt(0)" ::: "memory");                        \
    __builtin_amdgcn_s_setprio(1);                                            \
    _Pragma("unroll")                                                         \
    for (int mi4_ = 0; mi4_ < 4; ++mi4_)                                      \
      _Pragma("unroll")                                                       \
      for (int nj_ = 0; nj_ < 4; ++nj_)                                       \
        acc[(qm) * 4 + mi4_][nj_] = __builtin_amdgcn_mfma_f32_16x16x32_bf16(  \
            af_[mi4_], bf_[nj_], acc[(qm) * 4 + mi4_][nj_], 0, 0, 0);         \
    __builtin_amdgcn_s_setprio(0);                                            \
    VME;                                                                      \
    __builtin_amdgcn_s_barrier();                                             \
  } while (0)

  STAGE_A(0, 0, 0); STAGE_B(0, 0, 0); STAGE_A(0, 1, 0); STAGE_B(0, 1, 0);
  asm volatile("s_waitcnt vmcnt(4)" ::: "memory");
  __builtin_amdgcn_s_barrier();

  for (int t = 0; t < 7; ++t) {
    const int j1 = 2 * t + 1, j2 = 2 * t + 2;
    PHASE(0, 0, 0, STAGE_A(1, 0, j1), NOVM);
    PHASE(0, 0, 1, STAGE_B(1, 0, j1), VM4);
    PHASE(0, 1, 0, STAGE_A(1, 1, j1), NOVM);
    PHASE(0, 1, 1, STAGE_B(1, 1, j1), VM4);
    PHASE(1, 0, 0, STAGE_A(0, 0, j2), NOVM);
    PHASE(1, 0, 1, STAGE_B(0, 0, j2), VM4);
    PHASE(1, 1, 0, STAGE_A(0, 1, j2), NOVM);
    PHASE(1, 1, 1, STAGE_B(0, 1, j2), VM4);
  }
  PHASE(0, 0, 0, STAGE_A(1, 0, 15), NOVM);
  PHASE(0, 0, 1, STAGE_B(1, 0, 15), VM4);
  PHASE(0, 1, 0, STAGE_A(1, 1, 15), NOVM);
  PHASE(0, 1, 1, STAGE_B(1, 1, 15), VM4);
  PHASE(1, 0, 0, NOSTAGE, NOVM);
  PHASE(1, 0, 1, NOSTAGE, VM0);
  PHASE(1, 1, 0, NOSTAGE, NOVM);
  PHASE(1, 1, 1, NOSTAGE, NOVM);

#undef PHASE
#undef STAGE_A
#undef STAGE_B

#pragma unroll
  for (int mi = 0; mi < 8; ++mi) {
    const int row = m0 + wr * 128 + mi * 16 + g4 * 4;
#pragma unroll
    for (int nj = 0; nj < 4; ++nj) {
      const int col = n0 + wc * 64 + nj * 16 + ln15;
      const float bv = bias[col];
#pragma unroll
      for (int r = 0; r < 4; ++r)
        C[(size_t)(row + r) * 1024 + col] = acc[mi][nj][r] + bv;
    }
  }
}

// ---------------------------------------------------------------------------
// Windowed attention v3: block = (head, batch, t-chunk); 4 waves each own a
// 16-token tile; 2 iterations cover the 128-token chunk. Q/K head-major.
__global__ __launch_bounds__(256)
void attn3_k(const bf16_t* __restrict__ Q, const bf16_t* __restrict__ Kv,
             const bf16_t* __restrict__ Vt, const int* __restrict__ rr,
             bf16_t* __restrict__ O) {
  __shared__ __align__(16) bf16_t Pl[4][16][168];
  const int tid = threadIdx.x;
  const int wv = tid >> 6, ln = tid & 63, ln15 = ln & 15, g4 = ln >> 4;
  const int h = blockIdx.x, b = blockIdx.y, tc = blockIdx.z;
  bf16_t(*Pw)[168] = Pl[wv];
  const bf16_t* vb = Vt + ((size_t)(b * cH + h)) * cHD * cVTP;
  const bf16_t* qb = Q + ((size_t)(b * cH + h)) * cP * cHD;
  const bf16_t* kb = Kv + ((size_t)(b * cH + h)) * cP * cHD;

  for (int sub = 0; sub < 2; ++sub) {
    const int t0 = (tc * 2 + sub) * 64 + wv * 16;
    const int sbase = t0 - 128;

    int rv[4];
#pragma unroll
    for (int r = 0; r < 4; ++r) rv[r] = rr[b * cP + t0 + g4 * 4 + r];

    // Q A-frag: m = ln15 (t), k = g4*8+j (hd)
    const bf16_t* qp = qb + (size_t)(t0 + ln15) * cHD + g4 * 8;
    const bf16x8 qa0 = *(const bf16x8*)qp;
    const bf16x8 qa1 = *(const bf16x8*)(qp + 32);

    // QK^T over 9 s-chunks of 16 (s in [t0-128, t0+15])
    f32x4 lg[9];
#pragma unroll
    for (int c = 0; c < 9; ++c) {
      const int s = sbase + c * 16 + ln15;  // B-frag n = ln15 (s), k = hd
      bf16x8 k0v, k1v;
      if ((unsigned)s < (unsigned)cP) {
        const bf16_t* kp = kb + (size_t)s * cHD + g4 * 8;
        k0v = *(const bf16x8*)kp;
        k1v = *(const bf16x8*)(kp + 32);
      } else {
#pragma unroll
        for (int z = 0; z < 8; ++z) { k0v[z] = (bf16_t)0.f; k1v[z] = (bf16_t)0.f; }
      }
      f32x4 a = {0.f, 0.f, 0.f, 0.f};
      a = __builtin_amdgcn_mfma_f32_16x16x32_bf16(qa0, k0v, a, 0, 0, 0);
      a = __builtin_amdgcn_mfma_f32_16x16x32_bf16(qa1, k1v, a, 0, 0, 0);
      lg[c] = a;
    }

    // mask + scale; C layout: col(s)=ln15, row(t)=g4*4+reg
    float mx[4] = {-1e30f, -1e30f, -1e30f, -1e30f};
#pragma unroll
    for (int c = 0; c < 9; ++c)
#pragma unroll
      for (int r = 0; r < 4; ++r) {
        const int s = sbase + c * 16 + ln15;
        const int t = t0 + g4 * 4 + r;
        const bool ok = (s >= rv[r]) && (s <= t) && (t - s < cW);
        const float l = ok ? lg[c][r] * cSCALE : -1e30f;
        lg[c][r] = l;
        mx[r] = fmaxf(mx[r], l);
      }
#pragma unroll
    for (int r = 0; r < 4; ++r) {
      mx[r] = fmaxf(mx[r], __shfl_xor(mx[r], 1));
      mx[r] = fmaxf(mx[r], __shfl_xor(mx[r], 2));
      mx[r] = fmaxf(mx[r], __shfl_xor(mx[r], 4));
      mx[r] = fmaxf(mx[r], __shfl_xor(mx[r], 8));
    }
    float sm[4] = {0.f, 0.f, 0.f, 0.f};
#pragma unroll
    for (int c = 0; c < 9; ++c)
#pragma unroll
      for (int r = 0; r < 4; ++r) {
        const float e = __expf(lg[c][r] - mx[r]);
        lg[c][r] = e;
        sm[r] += e;
      }
#pragma unroll
    for (int r = 0; r < 4; ++r) {
      sm[r] += __shfl_xor(sm[r], 1);
      sm[r] += __shfl_xor(sm[r], 2);
      sm[r] += __shfl_xor(sm[r], 4);
      sm[r] += __shfl_xor(sm[r], 8);
    }
    float inv[4];
#pragma unroll
    for (int r = 0; r < 4; ++r) inv[r] = 1.f / sm[r];

    // P -> LDS (C-layout write), zero pad cols 144..159 for the 5th PV chunk
#pragma unroll
    for (int c = 0; c < 9; ++c)
#pragma unroll
      for (int r = 0; r < 4; ++r)
        Pw[g4 * 4 + r][c * 16 + ln15] = (bf16_t)(lg[c][r] * inv[r]);
#pragma unroll
    for (int z = 0; z < 4; ++z)
      Pw[ln15][144 + g4 * 4 + z] = (bf16_t)0.f;

    // PV: A = P (m=t, k=s from LDS), B = Vt rows (n=hd, k=s contiguous)
    f32x4 oacc[4];
#pragma unroll
    for (int j = 0; j < 4; ++j) oacc[j] = {0.f, 0.f, 0.f, 0.f};
#pragma unroll
    for (int c2 = 0; c2 < 5; ++c2) {
      const bf16x8 pa = *(const bf16x8*)(&Pw[ln15][c2 * 32 + g4 * 8]);
#pragma unroll
      for (int j = 0; j < 4; ++j) {
        const bf16x8 vf =
            *(const bf16x8*)(vb + (size_t)(j * 16 + ln15) * cVTP + (t0 + c2 * 32 + g4 * 8));
        oacc[j] = __builtin_amdgcn_mfma_f32_16x16x32_bf16(pa, vf, oacc[j], 0, 0, 0);
      }
    }
#pragma unroll
    for (int j = 0; j < 4; ++j) {
      const int col = h * cHD + j * 16 + ln15;
#pragma unroll
      for (int r = 0; r < 4; ++r)
        O[((size_t)(b * cP + t0 + g4 * 4 + r)) * cDWM + col] = (bf16_t)oacc[j][r];
    }
  }
}

// ---------------------------------------------------------------------------
extern "C" void kernel_launch(void* const* d_in, const int* in_sizes, int n_in,
                              void* d_out, int out_size, void* d_ws, size_t ws_size,
                              hipStream_t stream) {
  (void)in_sizes; (void)n_in; (void)out_size; (void)ws_size;
  const float* x  = (const float*)d_in[0];
  const int* mask = (const int*)d_in[1];
  const float* Wq = (const float*)d_in[2];
  const float* bq = (const float*)d_in[3];
  const float* Wk = (const float*)d_in[4];
  const float* bk = (const float*)d_in[5];
  const float* Wv = (const float*)d_in[6];
  const float* bv = (const float*)d_in[7];
  const float* Wo = (const float*)d_in[8];
  const float* bo = (const float*)d_in[9];
  float* out = (float*)d_out;

  char* ws = (char*)d_ws;
  size_t off = 0;
  bf16_t* Xbf = (bf16_t*)(ws + off); off += (size_t)cM * cD * 2;          // 64 MiB
  bf16_t* Wqt = (bf16_t*)(ws + off); off += (size_t)cD * cDWM * 2;        // contiguous
  bf16_t* Wkt = (bf16_t*)(ws + off); off += (size_t)cD * cDWM * 2;        //   [3072][1024]
  bf16_t* Wvt = (bf16_t*)(ws + off); off += (size_t)cD * cDWM * 2;        //   QKV block
  bf16_t* Wot = (bf16_t*)(ws + off); off += (size_t)cDWM * cD * 2;
  bf16_t* Qh  = (bf16_t*)(ws + off); off += (size_t)cM * cDWM * 2;        // 64 MiB
  bf16_t* Kh  = (bf16_t*)(ws + off); off += (size_t)cM * cDWM * 2;        // 64 MiB
  bf16_t* Vt  = (bf16_t*)(ws + off); off += (size_t)cBS * cH * cHD * cVTP * 2;  // 84 MiB
  int* rbuf   = (int*)(ws + off);    off += (size_t)cBS * cP * 4;
  bf16_t* Ob  = Xbf;  // X no longer needed after the QKV projection

  cvt_x_k<<<(cM * cD / 4 + 255) / 256, 256, 0, stream>>>(x, Xbf, cM * cD);
  cvt_wt_k<<<dim3(32, 32, 4), 256, 0, stream>>>(Wq, Wk, Wv, Wo, Wqt, Wkt, Wvt, Wot);
  resets2_k<<<cBS, cP, 0, stream>>>(mask, rbuf);

  gemm_qkv8_k<<<dim3(12, 128), 512, 0, stream>>>(Xbf, Wqt, bq, bk, bv, Qh, Kh, Vt);

  attn3_k<<<dim3(cH, cBS, 4), 256, 0, stream>>>(Qh, Kh, Vt, rbuf, Ob);

  gemm_bt8_k<<<dim3(4, 128), 512, 0, stream>>>(Ob, Wot, bo, out);
}

// Round 10
// 498.240 us; speedup vs baseline: 1.1931x; 1.0462x over previous
//
#include <hip/hip_runtime.h>
#include <stdint.h>

typedef __bf16 bf16_t;
typedef __bf16 bf16x8 __attribute__((ext_vector_type(8)));
typedef __bf16 bf16x4 __attribute__((ext_vector_type(4)));
typedef float  f32x4  __attribute__((ext_vector_type(4)));

constexpr int cBS = 64, cP = 512, cD = 1024, cDWM = 1024, cH = 16, cHD = 64, cW = 128;
constexpr int cVTP = 672;           // padded p-extent of Vt (sp = p + 128, max used 656)
constexpr int cM = cBS * cP;        // 32768
constexpr float cSCALE = 0.125f;    // 1/sqrt(64)

__device__ __forceinline__ void gld_lds16(const void* g, void* l) {
#if __has_builtin(__builtin_amdgcn_global_load_lds)
  __builtin_amdgcn_global_load_lds(
      (__attribute__((address_space(1))) void*)g,
      (__attribute__((address_space(3))) void*)l, 16, 0, 0);
#else
  *(bf16x8*)l = *(const bf16x8*)g;
#endif
}

// ---------------------------------------------------------------------------
// fp32 -> bf16 conversion of X
__global__ void cvt_x_k(const float* __restrict__ X, bf16_t* __restrict__ Y, int n) {
  int i = (blockIdx.x * blockDim.x + threadIdx.x) * 4;
  if (i >= n) return;
  float4 v = *(const float4*)(X + i);
  bf16x4 o;
  o[0] = (bf16_t)v.x; o[1] = (bf16_t)v.y; o[2] = (bf16_t)v.z; o[3] = (bf16_t)v.w;
  *(bf16x4*)(Y + i) = o;
}

// transpose + convert the four 1024x1024 weights: W[k][n] fp32 -> Wt[n][k] bf16
__global__ void cvt_wt_k(const float* __restrict__ W0, const float* __restrict__ W1,
                         const float* __restrict__ W2, const float* __restrict__ W3,
                         bf16_t* __restrict__ T0, bf16_t* __restrict__ T1,
                         bf16_t* __restrict__ T2, bf16_t* __restrict__ T3) {
  __shared__ float tile[32][33];
  const float* Wsrc; bf16_t* Tdst;
  switch (blockIdx.z) {
    case 0: Wsrc = W0; Tdst = T0; break;
    case 1: Wsrc = W1; Tdst = T1; break;
    case 2: Wsrc = W2; Tdst = T2; break;
    default: Wsrc = W3; Tdst = T3; break;
  }
  const int n0 = blockIdx.x * 32, k0 = blockIdx.y * 32;
  const int c = threadIdx.x & 31, r8 = threadIdx.x >> 5;
#pragma unroll
  for (int q = 0; q < 4; ++q) {
    int row = r8 + q * 8;
    tile[row][c] = Wsrc[(size_t)(k0 + row) * 1024 + n0 + c];
  }
  __syncthreads();
#pragma unroll
  for (int q = 0; q < 4; ++q) {
    int row = r8 + q * 8;
    Tdst[(size_t)(n0 + row) * 1024 + k0 + c] = (bf16_t)tile[c][row];
  }
}

// r[b][t] = index of last reset at-or-before t (0 if none): parallel max-scan
__global__ void resets2_k(const int* __restrict__ mask, int* __restrict__ r) {
  __shared__ int sm[cP];
  const int b = blockIdx.x, t = threadIdx.x;
  sm[t] = mask[b * cP + t] ? t : 0;
  __syncthreads();
#pragma unroll
  for (int d = 1; d < cP; d <<= 1) {
    int u = (t >= d) ? sm[t - d] : 0;
    __syncthreads();
    if (u > sm[t]) sm[t] = u;
    __syncthreads();
  }
  r[b * cP + t] = sm[t];
}

// ---------------------------------------------------------------------------
// Fused QKV GEMM, 256x256 tile, 8-phase pipelined — EXACT Round-1 variant
// (fastest measured: 253 us, MfmaUtil 35).
// C[M][3072] = A[M][1024] * Wt[3072][1024]^T.
// Seg 0 -> Q head-major [b][h][p][hd], 1 -> K head-major, 2 -> Vt [b][h][hd][sp].
__global__ __launch_bounds__(512, 2)
void gemm_qkv8_k(const bf16_t* __restrict__ A, const bf16_t* __restrict__ Wt,
                 const float* __restrict__ bq, const float* __restrict__ bk,
                 const float* __restrict__ bvv,
                 bf16_t* __restrict__ Qh, bf16_t* __restrict__ Kh,
                 bf16_t* __restrict__ Vt) {
  __shared__ __align__(16) char LDS[131072];
  const int tid = threadIdx.x;
  const int wid = tid >> 6, ln = tid & 63;
  const int ln15 = ln & 15, g4 = ln >> 4;
  const int wr = wid >> 2, wc = wid & 3;   // wave -> (row half, col quarter)

  // XCD swizzle: per-XCD m-slice, n-fastest so the A-panel stays L2-resident
  const int g = blockIdx.x + 12 * blockIdx.y;   // [0, 1536)
  const int xcd = g & 7, s = g >> 3;            // s in [0, 192)
  const int nb = s % 12, mloc = s / 12;         // mloc in [0, 16)
  const int m0 = (xcd * 16 + mloc) * 256, n0 = nb * 256;

  const bf16_t* Ab = A + (size_t)m0 * 1024;
  const bf16_t* Bb = Wt + (size_t)n0 * 1024;

  // staging: thread covers 16B chunks q = i*512+tid; row=q>>2, phys slot=q&3,
  // logical slot = phys ^ (row&3) (involution) taken from the GLOBAL source.
  const int srow = tid >> 2;                        // 0..127 (i=1 adds 128)
  const int gslot = (tid & 3) ^ (srow & 3);
  const size_t aoff = (size_t)srow * 1024 + (size_t)(gslot * 8);
  char* const lbase = LDS + tid * 16;

  // ds_read lane addressing: row = <frag base> + ln15 (row&3 == ln15&3),
  // logical k-chunk g4 lives at phys slot g4 ^ (ln15&3).
  const int slotr = (g4 ^ (ln15 & 3)) << 4;
  const int abase = (wr * 128 + ln15) * 64 + slotr;          // + mi*1024
  const int bbase = 32768 + (wc * 64 + ln15) * 64 + slotr;   // + nj*1024

  f32x4 acc[8][4];
#pragma unroll
  for (int i = 0; i < 8; ++i)
#pragma unroll
    for (int j = 0; j < 4; ++j) acc[i][j] = {0.f, 0.f, 0.f, 0.f};

#define STAGE_A(buf, kh, j) do {                                              \
    const bf16_t* gp_ = Ab + (size_t)((j) * 64 + (kh) * 32) + aoff;           \
    char* lp_ = lbase + (buf) * 65536 + (kh) * 16384;                         \
    gld_lds16(gp_, lp_);                                                      \
    gld_lds16(gp_ + (size_t)128 * 1024, lp_ + 8192);                          \
  } while (0)

#define STAGE_B(buf, kh, j) do {                                              \
    const bf16_t* gp_ = Bb + (size_t)((j) * 64 + (kh) * 32) + aoff;           \
    char* lp_ = lbase + (buf) * 65536 + (kh) * 16384 + 32768;                 \
    gld_lds16(gp_, lp_);                                                      \
    gld_lds16(gp_ + (size_t)128 * 1024, lp_ + 8192);                          \
  } while (0)

#define NOSTAGE ((void)0)
#define VM4 asm volatile("s_waitcnt vmcnt(4)" ::: "memory")
#define VM0 asm volatile("s_waitcnt vmcnt(0)" ::: "memory")
#define NOVM ((void)0)

#define PHASE(buf, kh, qm, STAGE, VME) do {                                   \
    const char* Ar_ = LDS + (buf) * 65536 + (kh) * 16384 + abase + (qm) * 4096;\
    const char* Br_ = LDS + (buf) * 65536 + (kh) * 16384 + bbase;             \
    bf16x8 af_[4], bf_[4];                                                    \
    af_[0] = *(const bf16x8*)(Ar_);                                           \
    af_[1] = *(const bf16x8*)(Ar_ + 1024);                                    \
    af_[2] = *(const bf16x8*)(Ar_ + 2048);                                    \
    af_[3] = *(const bf16x8*)(Ar_ + 3072);                                    \
    bf_[0] = *(const bf16x8*)(Br_);                                           \
    bf_[1] = *(const bf16x8*)(Br_ + 1024);                                    \
    bf_[2] = *(const bf16x8*)(Br_ + 2048);                                    \
    bf_[3] = *(const bf16x8*)(Br_ + 3072);                                    \
    STAGE;                                                                    \
    __builtin_amdgcn_s_barrier();                                             \
    asm volatile("s_waitcnt lgkmcnt(0)" ::: "memory");                        \
    __builtin_amdgcn_s_setprio(1);                                            \
    _Pragma("unroll")                                                         \
    for (int mi4_ = 0; mi4_ < 4; ++mi4_)                                      \
      _Pragma("unroll")                                                       \
      for (int nj_ = 0; nj_ < 4; ++nj_)                                       \
        acc[(qm) * 4 + mi4_][nj_] = __builtin_amdgcn_mfma_f32_16x16x32_bf16(  \
            af_[mi4_], bf_[nj_], acc[(qm) * 4 + mi4_][nj_], 0, 0, 0);         \
    __builtin_amdgcn_s_setprio(0);                                            \
    VME;                                                                      \
    __builtin_amdgcn_s_barrier();                                             \
  } while (0)

  // prologue: tile0 (4 stages, 8 loads); drain its kh0 A+B (oldest 4 loads)
  STAGE_A(0, 0, 0); STAGE_B(0, 0, 0); STAGE_A(0, 1, 0); STAGE_B(0, 1, 0);
  asm volatile("s_waitcnt vmcnt(4)" ::: "memory");
  __builtin_amdgcn_s_barrier();

  for (int t = 0; t < 7; ++t) {
    const int j1 = 2 * t + 1, j2 = 2 * t + 2;
    PHASE(0, 0, 0, STAGE_A(1, 0, j1), NOVM);
    PHASE(0, 0, 1, STAGE_B(1, 0, j1), VM4);
    PHASE(0, 1, 0, STAGE_A(1, 1, j1), NOVM);
    PHASE(0, 1, 1, STAGE_B(1, 1, j1), VM4);
    PHASE(1, 0, 0, STAGE_A(0, 0, j2), NOVM);
    PHASE(1, 0, 1, STAGE_B(0, 0, j2), VM4);
    PHASE(1, 1, 0, STAGE_A(0, 1, j2), NOVM);
    PHASE(1, 1, 1, STAGE_B(0, 1, j2), VM4);
  }
  // tail: tiles 14,15; only tile15 still needs staging
  PHASE(0, 0, 0, STAGE_A(1, 0, 15), NOVM);
  PHASE(0, 0, 1, STAGE_B(1, 0, 15), VM4);
  PHASE(0, 1, 0, STAGE_A(1, 1, 15), NOVM);
  PHASE(0, 1, 1, STAGE_B(1, 1, 15), VM4);
  PHASE(1, 0, 0, NOSTAGE, NOVM);
  PHASE(1, 0, 1, NOSTAGE, VM0);
  PHASE(1, 1, 0, NOSTAGE, NOVM);
  PHASE(1, 1, 1, NOSTAGE, NOVM);

#undef PHASE
#undef STAGE_A
#undef STAGE_B

  const int seg = n0 >> 10;                      // block-uniform: 0=Q 1=K 2=V
  const float* bias = (seg == 0) ? bq : (seg == 1) ? bk : bvv;
  bf16_t* QK = (seg == 0) ? Qh : Kh;
#pragma unroll
  for (int mi = 0; mi < 8; ++mi) {
    const int rbase = m0 + wr * 128 + mi * 16 + g4 * 4;
    const int b = rbase >> 9, pb = rbase & 511;
#pragma unroll
    for (int nj = 0; nj < 4; ++nj) {
      const int col = n0 + wc * 64 + nj * 16 + ln15;
      const int cl = col & 1023;
      const int h = cl >> 6, hd = cl & 63;
      const float bv = bias[cl];
      if (seg < 2) {
        // head-major: [b][h][p][hd]
#pragma unroll
        for (int r = 0; r < 4; ++r)
          QK[(((size_t)(b * cH + h)) * cP + pb + r) * cHD + hd] =
              (bf16_t)(acc[mi][nj][r] + bv);
      } else {
        bf16x4 pk;
#pragma unroll
        for (int r = 0; r < 4; ++r) pk[r] = (bf16_t)(acc[mi][nj][r] + bv);
        *(bf16x4*)(Vt + ((size_t)((b * cH + h) * cHD + hd)) * cVTP + 128 + pb) = pk;
      }
    }
  }
}

// ---------------------------------------------------------------------------
// Output-projection GEMM: SAME verified 8-phase 256x256 structure as qkv
// (R0->R1 measured +18% vs 2-phase 128^2), fp32 output + bias epilogue.
// C[32768][1024] = Ob[32768][1024] * Wot[1024][1024]^T, grid 512 = 8x16x4.
__global__ __launch_bounds__(512, 2)
void gemm_bt8_k(const bf16_t* __restrict__ A, const bf16_t* __restrict__ Bt,
                const float* __restrict__ bias, float* __restrict__ C) {
  __shared__ __align__(16) char LDS[131072];
  const int tid = threadIdx.x;
  const int wid = tid >> 6, ln = tid & 63;
  const int ln15 = ln & 15, g4 = ln >> 4;
  const int wr = wid >> 2, wc = wid & 3;

  const int g = blockIdx.x + 4 * blockIdx.y;    // [0, 512)
  const int xcd = g & 7, s = g >> 3;            // s in [0, 64)
  const int nb = s & 3, mloc = s >> 2;          // mloc in [0, 16)
  const int m0 = (xcd * 16 + mloc) * 256, n0 = nb * 256;

  const bf16_t* Ab = A + (size_t)m0 * 1024;
  const bf16_t* Bb = Bt + (size_t)n0 * 1024;

  const int srow = tid >> 2;
  const int gslot = (tid & 3) ^ (srow & 3);
  const size_t aoff = (size_t)srow * 1024 + (size_t)(gslot * 8);
  char* const lbase = LDS + tid * 16;

  const int slotr = (g4 ^ (ln15 & 3)) << 4;
  const int abase = (wr * 128 + ln15) * 64 + slotr;
  const int bbase = 32768 + (wc * 64 + ln15) * 64 + slotr;

  f32x4 acc[8][4];
#pragma unroll
  for (int i = 0; i < 8; ++i)
#pragma unroll
    for (int j = 0; j < 4; ++j) acc[i][j] = {0.f, 0.f, 0.f, 0.f};

#define STAGE_A(buf, kh, j) do {                                              \
    const bf16_t* gp_ = Ab + (size_t)((j) * 64 + (kh) * 32) + aoff;           \
    char* lp_ = lbase + (buf) * 65536 + (kh) * 16384;                         \
    gld_lds16(gp_, lp_);                                                      \
    gld_lds16(gp_ + (size_t)128 * 1024, lp_ + 8192);                          \
  } while (0)

#define STAGE_B(buf, kh, j) do {                                              \
    const bf16_t* gp_ = Bb + (size_t)((j) * 64 + (kh) * 32) + aoff;           \
    char* lp_ = lbase + (buf) * 65536 + (kh) * 16384 + 32768;                 \
    gld_lds16(gp_, lp_);                                                      \
    gld_lds16(gp_ + (size_t)128 * 1024, lp_ + 8192);                          \
  } while (0)

#define NOSTAGE ((void)0)
#define VM4 asm volatile("s_waitcnt vmcnt(4)" ::: "memory")
#define VM0 asm volatile("s_waitcnt vmcnt(0)" ::: "memory")
#define NOVM ((void)0)

#define PHASE(buf, kh, qm, STAGE, VME) do {                                   \
    const char* Ar_ = LDS + (buf) * 65536 + (kh) * 16384 + abase + (qm) * 4096;\
    const char* Br_ = LDS + (buf) * 65536 + (kh) * 16384 + bbase;             \
    bf16x8 af_[4], bf_[4];                                                    \
    af_[0] = *(const bf16x8*)(Ar_);                                           \
    af_[1] = *(const bf16x8*)(Ar_ + 1024);                                    \
    af_[2] = *(const bf16x8*)(Ar_ + 2048);                                    \
    af_[3] = *(const bf16x8*)(Ar_ + 3072);                                    \
    bf_[0] = *(const bf16x8*)(Br_);                                           \
    bf_[1] = *(const bf16x8*)(Br_ + 1024);                                    \
    bf_[2] = *(const bf16x8*)(Br_ + 2048);                                    \
    bf_[3] = *(const bf16x8*)(Br_ + 3072);                                    \
    STAGE;                                                                    \
    __builtin_amdgcn_s_barrier();                                             \
    asm volatile("s_waitcnt lgkmcnt(0)" ::: "memory");                        \
    __builtin_amdgcn_s_setprio(1);                                            \
    _Pragma("unroll")                                                         \
    for (int mi4_ = 0; mi4_ < 4; ++mi4_)                                      \
      _Pragma("unroll")                                                       \
      for (int nj_ = 0; nj_ < 4; ++nj_)                                       \
        acc[(qm) * 4 + mi4_][nj_] = __builtin_amdgcn_mfma_f32_16x16x32_bf16(  \
            af_[mi4_], bf_[nj_], acc[(qm) * 4 + mi4_][nj_], 0, 0, 0);         \
    __builtin_amdgcn_s_setprio(0);                                            \
    VME;                                                                      \
    __builtin_amdgcn_s_barrier();                                             \
  } while (0)

  STAGE_A(0, 0, 0); STAGE_B(0, 0, 0); STAGE_A(0, 1, 0); STAGE_B(0, 1, 0);
  asm volatile("s_waitcnt vmcnt(4)" ::: "memory");
  __builtin_amdgcn_s_barrier();

  for (int t = 0; t < 7; ++t) {
    const int j1 = 2 * t + 1, j2 = 2 * t + 2;
    PHASE(0, 0, 0, STAGE_A(1, 0, j1), NOVM);
    PHASE(0, 0, 1, STAGE_B(1, 0, j1), VM4);
    PHASE(0, 1, 0, STAGE_A(1, 1, j1), NOVM);
    PHASE(0, 1, 1, STAGE_B(1, 1, j1), VM4);
    PHASE(1, 0, 0, STAGE_A(0, 0, j2), NOVM);
    PHASE(1, 0, 1, STAGE_B(0, 0, j2), VM4);
    PHASE(1, 1, 0, STAGE_A(0, 1, j2), NOVM);
    PHASE(1, 1, 1, STAGE_B(0, 1, j2), VM4);
  }
  PHASE(0, 0, 0, STAGE_A(1, 0, 15), NOVM);
  PHASE(0, 0, 1, STAGE_B(1, 0, 15), VM4);
  PHASE(0, 1, 0, STAGE_A(1, 1, 15), NOVM);
  PHASE(0, 1, 1, STAGE_B(1, 1, 15), VM4);
  PHASE(1, 0, 0, NOSTAGE, NOVM);
  PHASE(1, 0, 1, NOSTAGE, VM0);
  PHASE(1, 1, 0, NOSTAGE, NOVM);
  PHASE(1, 1, 1, NOSTAGE, NOVM);

#undef PHASE
#undef STAGE_A
#undef STAGE_B

#pragma unroll
  for (int mi = 0; mi < 8; ++mi) {
    const int row = m0 + wr * 128 + mi * 16 + g4 * 4;
#pragma unroll
    for (int nj = 0; nj < 4; ++nj) {
      const int col = n0 + wc * 64 + nj * 16 + ln15;
      const float bv = bias[col];
#pragma unroll
      for (int r = 0; r < 4; ++r)
        C[(size_t)(row + r) * 1024 + col] = acc[mi][nj][r] + bv;
    }
  }
}

// ---------------------------------------------------------------------------
// Windowed attention v4: 8 waves, both 64-token halves concurrent
// (wave = (sub, tile)); coalesced O-write via in-LDS transpose (reuses the
// dead P buffer, wave-local, no barrier). Q/K head-major, Vt transposed.
__global__ __launch_bounds__(512)
void attn3_k(const bf16_t* __restrict__ Q, const bf16_t* __restrict__ Kv,
             const bf16_t* __restrict__ Vt, const int* __restrict__ rr,
             bf16_t* __restrict__ O) {
  __shared__ __align__(16) bf16_t Pl[8][16][168];
  const int tid = threadIdx.x;
  const int wv = tid >> 6, ln = tid & 63, ln15 = ln & 15, g4 = ln >> 4;
  const int sub = wv >> 2, wtile = wv & 3;
  const int h = blockIdx.x, b = blockIdx.y, tc = blockIdx.z;
  bf16_t(*Pw)[168] = Pl[wv];
  const bf16_t* vb = Vt + ((size_t)(b * cH + h)) * cHD * cVTP;
  const bf16_t* qb = Q + ((size_t)(b * cH + h)) * cP * cHD;
  const bf16_t* kb = Kv + ((size_t)(b * cH + h)) * cP * cHD;

  const int t0 = (tc * 2 + sub) * 64 + wtile * 16;
  const int sbase = t0 - 128;

  // mask lower bound: lo = max(reset_idx, t-127); upper bound s <= t
  int lo[4], tt[4];
#pragma unroll
  for (int r = 0; r < 4; ++r) {
    tt[r] = t0 + g4 * 4 + r;
    const int rv = rr[b * cP + tt[r]];
    lo[r] = rv > tt[r] - (cW - 1) ? rv : tt[r] - (cW - 1);
  }

  // Q A-frag: m = ln15 (t), k = g4*8+j (hd)
  const bf16_t* qp = qb + (size_t)(t0 + ln15) * cHD + g4 * 8;
  const bf16x8 qa0 = *(const bf16x8*)qp;
  const bf16x8 qa1 = *(const bf16x8*)(qp + 32);

  // QK^T over 9 s-chunks of 16 (s in [t0-128, t0+15])
  f32x4 lg[9];
#pragma unroll
  for (int c = 0; c < 9; ++c) {
    const int s = sbase + c * 16 + ln15;  // B-frag n = ln15 (s), k = hd
    bf16x8 k0v, k1v;
    if ((unsigned)s < (unsigned)cP) {
      const bf16_t* kp = kb + (size_t)s * cHD + g4 * 8;
      k0v = *(const bf16x8*)kp;
      k1v = *(const bf16x8*)(kp + 32);
    } else {
#pragma unroll
      for (int z = 0; z < 8; ++z) { k0v[z] = (bf16_t)0.f; k1v[z] = (bf16_t)0.f; }
    }
    f32x4 a = {0.f, 0.f, 0.f, 0.f};
    a = __builtin_amdgcn_mfma_f32_16x16x32_bf16(qa0, k0v, a, 0, 0, 0);
    a = __builtin_amdgcn_mfma_f32_16x16x32_bf16(qa1, k1v, a, 0, 0, 0);
    lg[c] = a;
  }

  // mask + scale; C layout: col(s)=ln15, row(t)=g4*4+reg
  float mx[4] = {-1e30f, -1e30f, -1e30f, -1e30f};
#pragma unroll
  for (int c = 0; c < 9; ++c)
#pragma unroll
    for (int r = 0; r < 4; ++r) {
      const int s = sbase + c * 16 + ln15;
      const bool ok = (s >= lo[r]) && (s <= tt[r]);
      const float l = ok ? lg[c][r] * cSCALE : -1e30f;
      lg[c][r] = l;
      mx[r] = fmaxf(mx[r], l);
    }
#pragma unroll
  for (int r = 0; r < 4; ++r) {
    mx[r] = fmaxf(mx[r], __shfl_xor(mx[r], 1));
    mx[r] = fmaxf(mx[r], __shfl_xor(mx[r], 2));
    mx[r] = fmaxf(mx[r], __shfl_xor(mx[r], 4));
    mx[r] = fmaxf(mx[r], __shfl_xor(mx[r], 8));
  }
  float sm[4] = {0.f, 0.f, 0.f, 0.f};
#pragma unroll
  for (int c = 0; c < 9; ++c)
#pragma unroll
    for (int r = 0; r < 4; ++r) {
      const float e = __expf(lg[c][r] - mx[r]);
      lg[c][r] = e;
      sm[r] += e;
    }
#pragma unroll
  for (int r = 0; r < 4; ++r) {
    sm[r] += __shfl_xor(sm[r], 1);
    sm[r] += __shfl_xor(sm[r], 2);
    sm[r] += __shfl_xor(sm[r], 4);
    sm[r] += __shfl_xor(sm[r], 8);
  }
  float inv[4];
#pragma unroll
  for (int r = 0; r < 4; ++r) inv[r] = 1.f / sm[r];

  // P -> LDS (C-layout write), zero pad cols 144..159 for the 5th PV chunk
#pragma unroll
  for (int c = 0; c < 9; ++c)
#pragma unroll
    for (int r = 0; r < 4; ++r)
      Pw[g4 * 4 + r][c * 16 + ln15] = (bf16_t)(lg[c][r] * inv[r]);
#pragma unroll
  for (int z = 0; z < 4; ++z)
    Pw[ln15][144 + g4 * 4 + z] = (bf16_t)0.f;

  // PV: A = P (m=t, k=s from LDS), B = Vt rows (n=hd, k=s contiguous)
  f32x4 oacc[4];
#pragma unroll
  for (int j = 0; j < 4; ++j) oacc[j] = {0.f, 0.f, 0.f, 0.f};
#pragma unroll
  for (int c2 = 0; c2 < 5; ++c2) {
    const bf16x8 pa = *(const bf16x8*)(&Pw[ln15][c2 * 32 + g4 * 8]);
#pragma unroll
    for (int j = 0; j < 4; ++j) {
      const bf16x8 vf =
          *(const bf16x8*)(vb + (size_t)(j * 16 + ln15) * cVTP + (t0 + c2 * 32 + g4 * 8));
      oacc[j] = __builtin_amdgcn_mfma_f32_16x16x32_bf16(pa, vf, oacc[j], 0, 0, 0);
    }
  }

  // O via in-LDS transpose (P is dead): Pw[row 0..15][col 0..63] = O tile,
  // then row-major bf16x4 (8B/lane) coalesced stores: 128B/row segments.
#pragma unroll
  for (int j = 0; j < 4; ++j)
#pragma unroll
    for (int r = 0; r < 4; ++r)
      Pw[g4 * 4 + r][j * 16 + ln15] = (bf16_t)(oacc[j][r]);
  const int orow = ln >> 4;            // 0..3
  const int oc4 = (ln & 15) * 4;       // 0..60
  bf16_t* ob = O + (size_t)(b * cP + t0) * cDWM + h * cHD + oc4;
#pragma unroll
  for (int pass = 0; pass < 4; ++pass) {
    const int row = orow + pass * 4;
    const bf16x4 v = *(const bf16x4*)(&Pw[row][oc4]);
    *(bf16x4*)(ob + (size_t)row * cDWM) = v;
  }
}

// ---------------------------------------------------------------------------
extern "C" void kernel_launch(void* const* d_in, const int* in_sizes, int n_in,
                              void* d_out, int out_size, void* d_ws, size_t ws_size,
                              hipStream_t stream) {
  (void)in_sizes; (void)n_in; (void)out_size; (void)ws_size;
  const float* x  = (const float*)d_in[0];
  const int* mask = (const int*)d_in[1];
  const float* Wq = (const float*)d_in[2];
  const float* bq = (const float*)d_in[3];
  const float* Wk = (const float*)d_in[4];
  const float* bk = (const float*)d_in[5];
  const float* Wv = (const float*)d_in[6];
  const float* bv = (const float*)d_in[7];
  const float* Wo = (const float*)d_in[8];
  const float* bo = (const float*)d_in[9];
  float* out = (float*)d_out;

  char* ws = (char*)d_ws;
  size_t off = 0;
  bf16_t* Xbf = (bf16_t*)(ws + off); off += (size_t)cM * cD * 2;          // 64 MiB
  bf16_t* Wqt = (bf16_t*)(ws + off); off += (size_t)cD * cDWM * 2;        // contiguous
  bf16_t* Wkt = (bf16_t*)(ws + off); off += (size_t)cD * cDWM * 2;        //   [3072][1024]
  bf16_t* Wvt = (bf16_t*)(ws + off); off += (size_t)cD * cDWM * 2;        //   QKV block
  bf16_t* Wot = (bf16_t*)(ws + off); off += (size_t)cDWM * cD * 2;
  bf16_t* Qh  = (bf16_t*)(ws + off); off += (size_t)cM * cDWM * 2;        // 64 MiB
  bf16_t* Kh  = (bf16_t*)(ws + off); off += (size_t)cM * cDWM * 2;        // 64 MiB
  bf16_t* Vt  = (bf16_t*)(ws + off); off += (size_t)cBS * cH * cHD * cVTP * 2;  // 84 MiB
  int* rbuf   = (int*)(ws + off);    off += (size_t)cBS * cP * 4;
  bf16_t* Ob  = Xbf;  // X no longer needed after the QKV projection

  cvt_x_k<<<(cM * cD / 4 + 255) / 256, 256, 0, stream>>>(x, Xbf, cM * cD);
  cvt_wt_k<<<dim3(32, 32, 4), 256, 0, stream>>>(Wq, Wk, Wv, Wo, Wqt, Wkt, Wvt, Wot);
  resets2_k<<<cBS, cP, 0, stream>>>(mask, rbuf);

  gemm_qkv8_k<<<dim3(12, 128), 512, 0, stream>>>(Xbf, Wqt, bq, bk, bv, Qh, Kh, Vt);

  attn3_k<<<dim3(cH, cBS, 4), 512, 0, stream>>>(Qh, Kh, Vt, rbuf, Ob);

  gemm_bt8_k<<<dim3(4, 128), 512, 0, stream>>>(Ob, Wot, bo, out);
}

// Round 11
// 475.119 us; speedup vs baseline: 1.2512x; 1.0487x over previous
//
#include <hip/hip_runtime.h>
#include <stdint.h>

typedef __bf16 bf16_t;
typedef __bf16 bf16x8 __attribute__((ext_vector_type(8)));
typedef __bf16 bf16x4 __attribute__((ext_vector_type(4)));
typedef float  f32x4  __attribute__((ext_vector_type(4)));

constexpr int cBS = 64, cP = 512, cD = 1024, cDWM = 1024, cH = 16, cHD = 64, cW = 128;
constexpr int cVTP = 672;           // padded p-extent of Vt (sp = p + 128, max used 656)
constexpr int cM = cBS * cP;        // 32768
constexpr float cSCALE = 0.125f;    // 1/sqrt(64)

__device__ __forceinline__ void gld_lds16(const void* g, void* l) {
#if __has_builtin(__builtin_amdgcn_global_load_lds)
  __builtin_amdgcn_global_load_lds(
      (__attribute__((address_space(1))) void*)g,
      (__attribute__((address_space(3))) void*)l, 16, 0, 0);
#else
  *(bf16x8*)l = *(const bf16x8*)g;
#endif
}

// ---------------------------------------------------------------------------
// fp32 -> bf16 conversion of X
__global__ void cvt_x_k(const float* __restrict__ X, bf16_t* __restrict__ Y, int n) {
  int i = (blockIdx.x * blockDim.x + threadIdx.x) * 4;
  if (i >= n) return;
  float4 v = *(const float4*)(X + i);
  bf16x4 o;
  o[0] = (bf16_t)v.x; o[1] = (bf16_t)v.y; o[2] = (bf16_t)v.z; o[3] = (bf16_t)v.w;
  *(bf16x4*)(Y + i) = o;
}

// transpose + convert the four 1024x1024 weights: W[k][n] fp32 -> Wt[n][k] bf16
__global__ void cvt_wt_k(const float* __restrict__ W0, const float* __restrict__ W1,
                         const float* __restrict__ W2, const float* __restrict__ W3,
                         bf16_t* __restrict__ T0, bf16_t* __restrict__ T1,
                         bf16_t* __restrict__ T2, bf16_t* __restrict__ T3) {
  __shared__ float tile[32][33];
  const float* Wsrc; bf16_t* Tdst;
  switch (blockIdx.z) {
    case 0: Wsrc = W0; Tdst = T0; break;
    case 1: Wsrc = W1; Tdst = T1; break;
    case 2: Wsrc = W2; Tdst = T2; break;
    default: Wsrc = W3; Tdst = T3; break;
  }
  const int n0 = blockIdx.x * 32, k0 = blockIdx.y * 32;
  const int c = threadIdx.x & 31, r8 = threadIdx.x >> 5;
#pragma unroll
  for (int q = 0; q < 4; ++q) {
    int row = r8 + q * 8;
    tile[row][c] = Wsrc[(size_t)(k0 + row) * 1024 + n0 + c];
  }
  __syncthreads();
#pragma unroll
  for (int q = 0; q < 4; ++q) {
    int row = r8 + q * 8;
    Tdst[(size_t)(n0 + row) * 1024 + k0 + c] = (bf16_t)tile[c][row];
  }
}

// r[b][t] = index of last reset at-or-before t (0 if none): parallel max-scan
__global__ void resets2_k(const int* __restrict__ mask, int* __restrict__ r) {
  __shared__ int sm[cP];
  const int b = blockIdx.x, t = threadIdx.x;
  sm[t] = mask[b * cP + t] ? t : 0;
  __syncthreads();
#pragma unroll
  for (int d = 1; d < cP; d <<= 1) {
    int u = (t >= d) ? sm[t - d] : 0;
    __syncthreads();
    if (u > sm[t]) sm[t] = u;
    __syncthreads();
  }
  r[b * cP + t] = sm[t];
}

// ---------------------------------------------------------------------------
// Fused QKV GEMM, 256x256 tile, 8-phase pipelined — EXACT Round-1 variant
// (fastest measured: 253 us, MfmaUtil 35).
// C[M][3072] = A[M][1024] * Wt[3072][1024]^T.
// Seg 0 -> Q head-major [b][h][p][hd], 1 -> K head-major, 2 -> Vt [b][h][hd][sp].
__global__ __launch_bounds__(512, 2)
void gemm_qkv8_k(const bf16_t* __restrict__ A, const bf16_t* __restrict__ Wt,
                 const float* __restrict__ bq, const float* __restrict__ bk,
                 const float* __restrict__ bvv,
                 bf16_t* __restrict__ Qh, bf16_t* __restrict__ Kh,
                 bf16_t* __restrict__ Vt) {
  __shared__ __align__(16) char LDS[131072];
  const int tid = threadIdx.x;
  const int wid = tid >> 6, ln = tid & 63;
  const int ln15 = ln & 15, g4 = ln >> 4;
  const int wr = wid >> 2, wc = wid & 3;   // wave -> (row half, col quarter)

  // XCD swizzle: per-XCD m-slice, n-fastest so the A-panel stays L2-resident
  const int g = blockIdx.x + 12 * blockIdx.y;   // [0, 1536)
  const int xcd = g & 7, s = g >> 3;            // s in [0, 192)
  const int nb = s % 12, mloc = s / 12;         // mloc in [0, 16)
  const int m0 = (xcd * 16 + mloc) * 256, n0 = nb * 256;

  const bf16_t* Ab = A + (size_t)m0 * 1024;
  const bf16_t* Bb = Wt + (size_t)n0 * 1024;

  // staging: thread covers 16B chunks q = i*512+tid; row=q>>2, phys slot=q&3,
  // logical slot = phys ^ (row&3) (involution) taken from the GLOBAL source.
  const int srow = tid >> 2;                        // 0..127 (i=1 adds 128)
  const int gslot = (tid & 3) ^ (srow & 3);
  const size_t aoff = (size_t)srow * 1024 + (size_t)(gslot * 8);
  char* const lbase = LDS + tid * 16;

  // ds_read lane addressing: row = <frag base> + ln15 (row&3 == ln15&3),
  // logical k-chunk g4 lives at phys slot g4 ^ (ln15&3).
  const int slotr = (g4 ^ (ln15 & 3)) << 4;
  const int abase = (wr * 128 + ln15) * 64 + slotr;          // + mi*1024
  const int bbase = 32768 + (wc * 64 + ln15) * 64 + slotr;   // + nj*1024

  f32x4 acc[8][4];
#pragma unroll
  for (int i = 0; i < 8; ++i)
#pragma unroll
    for (int j = 0; j < 4; ++j) acc[i][j] = {0.f, 0.f, 0.f, 0.f};

#define STAGE_A(buf, kh, j) do {                                              \
    const bf16_t* gp_ = Ab + (size_t)((j) * 64 + (kh) * 32) + aoff;           \
    char* lp_ = lbase + (buf) * 65536 + (kh) * 16384;                         \
    gld_lds16(gp_, lp_);                                                      \
    gld_lds16(gp_ + (size_t)128 * 1024, lp_ + 8192);                          \
  } while (0)

#define STAGE_B(buf, kh, j) do {                                              \
    const bf16_t* gp_ = Bb + (size_t)((j) * 64 + (kh) * 32) + aoff;           \
    char* lp_ = lbase + (buf) * 65536 + (kh) * 16384 + 32768;                 \
    gld_lds16(gp_, lp_);                                                      \
    gld_lds16(gp_ + (size_t)128 * 1024, lp_ + 8192);                          \
  } while (0)

#define NOSTAGE ((void)0)
#define VM4 asm volatile("s_waitcnt vmcnt(4)" ::: "memory")
#define VM0 asm volatile("s_waitcnt vmcnt(0)" ::: "memory")
#define NOVM ((void)0)

#define PHASE(buf, kh, qm, STAGE, VME) do {                                   \
    const char* Ar_ = LDS + (buf) * 65536 + (kh) * 16384 + abase + (qm) * 4096;\
    const char* Br_ = LDS + (buf) * 65536 + (kh) * 16384 + bbase;             \
    bf16x8 af_[4], bf_[4];                                                    \
    af_[0] = *(const bf16x8*)(Ar_);                                           \
    af_[1] = *(const bf16x8*)(Ar_ + 1024);                                    \
    af_[2] = *(const bf16x8*)(Ar_ + 2048);                                    \
    af_[3] = *(const bf16x8*)(Ar_ + 3072);                                    \
    bf_[0] = *(const bf16x8*)(Br_);                                           \
    bf_[1] = *(const bf16x8*)(Br_ + 1024);                                    \
    bf_[2] = *(const bf16x8*)(Br_ + 2048);                                    \
    bf_[3] = *(const bf16x8*)(Br_ + 3072);                                    \
    STAGE;                                                                    \
    __builtin_amdgcn_s_barrier();                                             \
    asm volatile("s_waitcnt lgkmcnt(0)" ::: "memory");                        \
    __builtin_amdgcn_s_setprio(1);                                            \
    _Pragma("unroll")                                                         \
    for (int mi4_ = 0; mi4_ < 4; ++mi4_)                                      \
      _Pragma("unroll")                                                       \
      for (int nj_ = 0; nj_ < 4; ++nj_)                                       \
        acc[(qm) * 4 + mi4_][nj_] = __builtin_amdgcn_mfma_f32_16x16x32_bf16(  \
            af_[mi4_], bf_[nj_], acc[(qm) * 4 + mi4_][nj_], 0, 0, 0);         \
    __builtin_amdgcn_s_setprio(0);                                            \
    VME;                                                                      \
    __builtin_amdgcn_s_barrier();                                             \
  } while (0)

  // prologue: tile0 (4 stages, 8 loads); drain its kh0 A+B (oldest 4 loads)
  STAGE_A(0, 0, 0); STAGE_B(0, 0, 0); STAGE_A(0, 1, 0); STAGE_B(0, 1, 0);
  asm volatile("s_waitcnt vmcnt(4)" ::: "memory");
  __builtin_amdgcn_s_barrier();

  for (int t = 0; t < 7; ++t) {
    const int j1 = 2 * t + 1, j2 = 2 * t + 2;
    PHASE(0, 0, 0, STAGE_A(1, 0, j1), NOVM);
    PHASE(0, 0, 1, STAGE_B(1, 0, j1), VM4);
    PHASE(0, 1, 0, STAGE_A(1, 1, j1), NOVM);
    PHASE(0, 1, 1, STAGE_B(1, 1, j1), VM4);
    PHASE(1, 0, 0, STAGE_A(0, 0, j2), NOVM);
    PHASE(1, 0, 1, STAGE_B(0, 0, j2), VM4);
    PHASE(1, 1, 0, STAGE_A(0, 1, j2), NOVM);
    PHASE(1, 1, 1, STAGE_B(0, 1, j2), VM4);
  }
  // tail: tiles 14,15; only tile15 still needs staging
  PHASE(0, 0, 0, STAGE_A(1, 0, 15), NOVM);
  PHASE(0, 0, 1, STAGE_B(1, 0, 15), VM4);
  PHASE(0, 1, 0, STAGE_A(1, 1, 15), NOVM);
  PHASE(0, 1, 1, STAGE_B(1, 1, 15), VM4);
  PHASE(1, 0, 0, NOSTAGE, NOVM);
  PHASE(1, 0, 1, NOSTAGE, VM0);
  PHASE(1, 1, 0, NOSTAGE, NOVM);
  PHASE(1, 1, 1, NOSTAGE, NOVM);

#undef PHASE
#undef STAGE_A
#undef STAGE_B

  const int seg = n0 >> 10;                      // block-uniform: 0=Q 1=K 2=V
  const float* bias = (seg == 0) ? bq : (seg == 1) ? bk : bvv;
  bf16_t* QK = (seg == 0) ? Qh : Kh;
#pragma unroll
  for (int mi = 0; mi < 8; ++mi) {
    const int rbase = m0 + wr * 128 + mi * 16 + g4 * 4;
    const int b = rbase >> 9, pb = rbase & 511;
#pragma unroll
    for (int nj = 0; nj < 4; ++nj) {
      const int col = n0 + wc * 64 + nj * 16 + ln15;
      const int cl = col & 1023;
      const int h = cl >> 6, hd = cl & 63;
      const float bv = bias[cl];
      if (seg < 2) {
        // head-major: [b][h][p][hd]
#pragma unroll
        for (int r = 0; r < 4; ++r)
          QK[(((size_t)(b * cH + h)) * cP + pb + r) * cHD + hd] =
              (bf16_t)(acc[mi][nj][r] + bv);
      } else {
        bf16x4 pk;
#pragma unroll
        for (int r = 0; r < 4; ++r) pk[r] = (bf16_t)(acc[mi][nj][r] + bv);
        *(bf16x4*)(Vt + ((size_t)((b * cH + h) * cHD + hd)) * cVTP + 128 + pb) = pk;
      }
    }
  }
}

// ---------------------------------------------------------------------------
// Output-projection GEMM: SAME verified 8-phase 256x256 structure as qkv,
// fp32 output + bias epilogue. Grid 512 = 8 XCD x 16 m x 4 n.
__global__ __launch_bounds__(512, 2)
void gemm_bt8_k(const bf16_t* __restrict__ A, const bf16_t* __restrict__ Bt,
                const float* __restrict__ bias, float* __restrict__ C) {
  __shared__ __align__(16) char LDS[131072];
  const int tid = threadIdx.x;
  const int wid = tid >> 6, ln = tid & 63;
  const int ln15 = ln & 15, g4 = ln >> 4;
  const int wr = wid >> 2, wc = wid & 3;

  const int g = blockIdx.x + 4 * blockIdx.y;    // [0, 512)
  const int xcd = g & 7, s = g >> 3;            // s in [0, 64)
  const int nb = s & 3, mloc = s >> 2;          // mloc in [0, 16)
  const int m0 = (xcd * 16 + mloc) * 256, n0 = nb * 256;

  const bf16_t* Ab = A + (size_t)m0 * 1024;
  const bf16_t* Bb = Bt + (size_t)n0 * 1024;

  const int srow = tid >> 2;
  const int gslot = (tid & 3) ^ (srow & 3);
  const size_t aoff = (size_t)srow * 1024 + (size_t)(gslot * 8);
  char* const lbase = LDS + tid * 16;

  const int slotr = (g4 ^ (ln15 & 3)) << 4;
  const int abase = (wr * 128 + ln15) * 64 + slotr;
  const int bbase = 32768 + (wc * 64 + ln15) * 64 + slotr;

  f32x4 acc[8][4];
#pragma unroll
  for (int i = 0; i < 8; ++i)
#pragma unroll
    for (int j = 0; j < 4; ++j) acc[i][j] = {0.f, 0.f, 0.f, 0.f};

#define STAGE_A(buf, kh, j) do {                                              \
    const bf16_t* gp_ = Ab + (size_t)((j) * 64 + (kh) * 32) + aoff;           \
    char* lp_ = lbase + (buf) * 65536 + (kh) * 16384;                         \
    gld_lds16(gp_, lp_);                                                      \
    gld_lds16(gp_ + (size_t)128 * 1024, lp_ + 8192);                          \
  } while (0)

#define STAGE_B(buf, kh, j) do {                                              \
    const bf16_t* gp_ = Bb + (size_t)((j) * 64 + (kh) * 32) + aoff;           \
    char* lp_ = lbase + (buf) * 65536 + (kh) * 16384 + 32768;                 \
    gld_lds16(gp_, lp_);                                                      \
    gld_lds16(gp_ + (size_t)128 * 1024, lp_ + 8192);                          \
  } while (0)

#define NOSTAGE ((void)0)
#define VM4 asm volatile("s_waitcnt vmcnt(4)" ::: "memory")
#define VM0 asm volatile("s_waitcnt vmcnt(0)" ::: "memory")
#define NOVM ((void)0)

#define PHASE(buf, kh, qm, STAGE, VME) do {                                   \
    const char* Ar_ = LDS + (buf) * 65536 + (kh) * 16384 + abase + (qm) * 4096;\
    const char* Br_ = LDS + (buf) * 65536 + (kh) * 16384 + bbase;             \
    bf16x8 af_[4], bf_[4];                                                    \
    af_[0] = *(const bf16x8*)(Ar_);                                           \
    af_[1] = *(const bf16x8*)(Ar_ + 1024);                                    \
    af_[2] = *(const bf16x8*)(Ar_ + 2048);                                    \
    af_[3] = *(const bf16x8*)(Ar_ + 3072);                                    \
    bf_[0] = *(const bf16x8*)(Br_);                                           \
    bf_[1] = *(const bf16x8*)(Br_ + 1024);                                    \
    bf_[2] = *(const bf16x8*)(Br_ + 2048);                                    \
    bf_[3] = *(const bf16x8*)(Br_ + 3072);                                    \
    STAGE;                                                                    \
    __builtin_amdgcn_s_barrier();                                             \
    asm volatile("s_waitcnt lgkmcnt(0)" ::: "memory");                        \
    __builtin_amdgcn_s_setprio(1);                                            \
    _Pragma("unroll")                                                         \
    for (int mi4_ = 0; mi4_ < 4; ++mi4_)                                      \
      _Pragma("unroll")                                                       \
      for (int nj_ = 0; nj_ < 4; ++nj_)                                       \
        acc[(qm) * 4 + mi4_][nj_] = __builtin_amdgcn_mfma_f32_16x16x32_bf16(  \
            af_[mi4_], bf_[nj_], acc[(qm) * 4 + mi4_][nj_], 0, 0, 0);         \
    __builtin_amdgcn_s_setprio(0);                                            \
    VME;                                                                      \
    __builtin_amdgcn_s_barrier();                                             \
  } while (0)

  STAGE_A(0, 0, 0); STAGE_B(0, 0, 0); STAGE_A(0, 1, 0); STAGE_B(0, 1, 0);
  asm volatile("s_waitcnt vmcnt(4)" ::: "memory");
  __builtin_amdgcn_s_barrier();

  for (int t = 0; t < 7; ++t) {
    const int j1 = 2 * t + 1, j2 = 2 * t + 2;
    PHASE(0, 0, 0, STAGE_A(1, 0, j1), NOVM);
    PHASE(0, 0, 1, STAGE_B(1, 0, j1), VM4);
    PHASE(0, 1, 0, STAGE_A(1, 1, j1), NOVM);
    PHASE(0, 1, 1, STAGE_B(1, 1, j1), VM4);
    PHASE(1, 0, 0, STAGE_A(0, 0, j2), NOVM);
    PHASE(1, 0, 1, STAGE_B(0, 0, j2), VM4);
    PHASE(1, 1, 0, STAGE_A(0, 1, j2), NOVM);
    PHASE(1, 1, 1, STAGE_B(0, 1, j2), VM4);
  }
  PHASE(0, 0, 0, STAGE_A(1, 0, 15), NOVM);
  PHASE(0, 0, 1, STAGE_B(1, 0, 15), VM4);
  PHASE(0, 1, 0, STAGE_A(1, 1, 15), NOVM);
  PHASE(0, 1, 1, STAGE_B(1, 1, 15), VM4);
  PHASE(1, 0, 0, NOSTAGE, NOVM);
  PHASE(1, 0, 1, NOSTAGE, VM0);
  PHASE(1, 1, 0, NOSTAGE, NOVM);
  PHASE(1, 1, 1, NOSTAGE, NOVM);

#undef PHASE
#undef STAGE_A
#undef STAGE_B

#pragma unroll
  for (int mi = 0; mi < 8; ++mi) {
    const int row = m0 + wr * 128 + mi * 16 + g4 * 4;
#pragma unroll
    for (int nj = 0; nj < 4; ++nj) {
      const int col = n0 + wc * 64 + nj * 16 + ln15;
      const float bv = bias[col];
#pragma unroll
      for (int r = 0; r < 4; ++r)
        C[(size_t)(row + r) * 1024 + col] = acc[mi][nj][r] + bv;
    }
  }
}

// ---------------------------------------------------------------------------
// Windowed attention v5: 8 waves, both halves concurrent; block's 256-token
// K-window staged ONCE into LDS in fragment order (coalesced global_load_lds,
// conflict-free b128 reads, 6x intra-block reuse). Rows with s<0 stage
// garbage from the preceding allocation -- always overwritten by the -1e30
// mask (same as the old zero-fill path). Coalesced O via in-LDS transpose.
__global__ __launch_bounds__(512)
void attn3_k(const bf16_t* __restrict__ Q, const bf16_t* __restrict__ Kv,
             const bf16_t* __restrict__ Vt, const int* __restrict__ rr,
             bf16_t* __restrict__ O) {
  __shared__ __align__(16) char LDSA[32768 + 8 * 16 * 168 * 2];
  char* const Kst = LDSA;                               // 32 KiB K window
  bf16_t(*Pl)[16][168] = (bf16_t(*)[16][168])(LDSA + 32768);
  const int tid = threadIdx.x;
  const int wv = tid >> 6, ln = tid & 63, ln15 = ln & 15, g4 = ln >> 4;
  const int sub = wv >> 2, wtile = wv & 3;
  const int h = blockIdx.x, b = blockIdx.y, tc = blockIdx.z;
  bf16_t(*Pw)[168] = Pl[wv];
  const bf16_t* vb = Vt + ((size_t)(b * cH + h)) * cHD * cVTP;
  const bf16_t* qb = Q + ((size_t)(b * cH + h)) * cP * cHD;
  const bf16_t* kb = Kv + ((size_t)(b * cH + h)) * cP * cHD;

  // --- cooperative K stage: rows s in [tc*128-128, tc*128+128) in frag order
  // chunk q (16B): subtile q>>7 (16 rows), row q&15, k-chunk (q>>4)&7;
  // LDS offset q*16 == frag-order address (subtile*2048 + (c*16+r)*16).
  const int sb0 = tc * 128 - 128;
#pragma unroll
  for (int i = 0; i < 4; ++i) {
    const int q = i * 512 + tid;
    const int st = q >> 7, r = q & 15, c = (q >> 4) & 7;
    const long srow = (long)(sb0 + st * 16 + r);
    gld_lds16(kb + srow * 64 + c * 8, Kst + q * 16);
  }
  __syncthreads();   // drains the LDS-DMA (vmcnt) + barrier

  const int t0 = (tc * 2 + sub) * 64 + wtile * 16;
  const int sbase = t0 - 128;
  const int lst = sub * 4 + wtile;    // local subtile base: (t0 - sb0)/16 - 8

  // mask lower bound: lo = max(reset_idx, t-127); upper bound s <= t
  int lo[4], tt[4];
#pragma unroll
  for (int r = 0; r < 4; ++r) {
    tt[r] = t0 + g4 * 4 + r;
    const int rv = rr[b * cP + tt[r]];
    lo[r] = rv > tt[r] - (cW - 1) ? rv : tt[r] - (cW - 1);
  }

  // Q A-frag: m = ln15 (t), k = g4*8+j (hd)
  const bf16_t* qp = qb + (size_t)(t0 + ln15) * cHD + g4 * 8;
  const bf16x8 qa0 = *(const bf16x8*)qp;
  const bf16x8 qa1 = *(const bf16x8*)(qp + 32);

  // QK^T over 9 s-chunks of 16 from the staged window
  const char* kfb = Kst + (g4 * 16 + ln15) * 16;
  f32x4 lg[9];
#pragma unroll
  for (int c = 0; c < 9; ++c) {
    const bf16x8 k0v = *(const bf16x8*)(kfb + (lst + c) * 2048);
    const bf16x8 k1v = *(const bf16x8*)(kfb + (lst + c) * 2048 + 1024);
    f32x4 a = {0.f, 0.f, 0.f, 0.f};
    a = __builtin_amdgcn_mfma_f32_16x16x32_bf16(qa0, k0v, a, 0, 0, 0);
    a = __builtin_amdgcn_mfma_f32_16x16x32_bf16(qa1, k1v, a, 0, 0, 0);
    lg[c] = a;
  }

  // mask + scale; C layout: col(s)=ln15, row(t)=g4*4+reg
  float mx[4] = {-1e30f, -1e30f, -1e30f, -1e30f};
#pragma unroll
  for (int c = 0; c < 9; ++c)
#pragma unroll
    for (int r = 0; r < 4; ++r) {
      const int s = sbase + c * 16 + ln15;
      const bool ok = (s >= lo[r]) && (s <= tt[r]);
      const float l = ok ? lg[c][r] * cSCALE : -1e30f;
      lg[c][r] = l;
      mx[r] = fmaxf(mx[r], l);
    }
#pragma unroll
  for (int r = 0; r < 4; ++r) {
    mx[r] = fmaxf(mx[r], __shfl_xor(mx[r], 1));
    mx[r] = fmaxf(mx[r], __shfl_xor(mx[r], 2));
    mx[r] = fmaxf(mx[r], __shfl_xor(mx[r], 4));
    mx[r] = fmaxf(mx[r], __shfl_xor(mx[r], 8));
  }
  float sm[4] = {0.f, 0.f, 0.f, 0.f};
#pragma unroll
  for (int c = 0; c < 9; ++c)
#pragma unroll
    for (int r = 0; r < 4; ++r) {
      const float e = __expf(lg[c][r] - mx[r]);
      lg[c][r] = e;
      sm[r] += e;
    }
#pragma unroll
  for (int r = 0; r < 4; ++r) {
    sm[r] += __shfl_xor(sm[r], 1);
    sm[r] += __shfl_xor(sm[r], 2);
    sm[r] += __shfl_xor(sm[r], 4);
    sm[r] += __shfl_xor(sm[r], 8);
  }
  float inv[4];
#pragma unroll
  for (int r = 0; r < 4; ++r) inv[r] = 1.f / sm[r];

  // P -> LDS (C-layout write), zero pad cols 144..159 for the 5th PV chunk
#pragma unroll
  for (int c = 0; c < 9; ++c)
#pragma unroll
    for (int r = 0; r < 4; ++r)
      Pw[g4 * 4 + r][c * 16 + ln15] = (bf16_t)(lg[c][r] * inv[r]);
#pragma unroll
  for (int z = 0; z < 4; ++z)
    Pw[ln15][144 + g4 * 4 + z] = (bf16_t)0.f;

  // PV: A = P (m=t, k=s from LDS), B = Vt rows (n=hd, k=s contiguous)
  f32x4 oacc[4];
#pragma unroll
  for (int j = 0; j < 4; ++j) oacc[j] = {0.f, 0.f, 0.f, 0.f};
#pragma unroll
  for (int c2 = 0; c2 < 5; ++c2) {
    const bf16x8 pa = *(const bf16x8*)(&Pw[ln15][c2 * 32 + g4 * 8]);
#pragma unroll
    for (int j = 0; j < 4; ++j) {
      const bf16x8 vf =
          *(const bf16x8*)(vb + (size_t)(j * 16 + ln15) * cVTP + (t0 + c2 * 32 + g4 * 8));
      oacc[j] = __builtin_amdgcn_mfma_f32_16x16x32_bf16(pa, vf, oacc[j], 0, 0, 0);
    }
  }

  // O via in-LDS transpose (P is dead): Pw[row 0..15][col 0..63] = O tile,
  // then row-major bf16x4 (8B/lane) coalesced stores: 128B/row segments.
#pragma unroll
  for (int j = 0; j < 4; ++j)
#pragma unroll
    for (int r = 0; r < 4; ++r)
      Pw[g4 * 4 + r][j * 16 + ln15] = (bf16_t)(oacc[j][r]);
  const int orow = ln >> 4;            // 0..3
  const int oc4 = (ln & 15) * 4;       // 0..60
  bf16_t* ob = O + (size_t)(b * cP + t0) * cDWM + h * cHD + oc4;
#pragma unroll
  for (int pass = 0; pass < 4; ++pass) {
    const int row = orow + pass * 4;
    const bf16x4 v = *(const bf16x4*)(&Pw[row][oc4]);
    *(bf16x4*)(ob + (size_t)row * cDWM) = v;
  }
}

// ---------------------------------------------------------------------------
extern "C" void kernel_launch(void* const* d_in, const int* in_sizes, int n_in,
                              void* d_out, int out_size, void* d_ws, size_t ws_size,
                              hipStream_t stream) {
  (void)in_sizes; (void)n_in; (void)out_size; (void)ws_size;
  const float* x  = (const float*)d_in[0];
  const int* mask = (const int*)d_in[1];
  const float* Wq = (const float*)d_in[2];
  const float* bq = (const float*)d_in[3];
  const float* Wk = (const float*)d_in[4];
  const float* bk = (const float*)d_in[5];
  const float* Wv = (const float*)d_in[6];
  const float* bv = (const float*)d_in[7];
  const float* Wo = (const float*)d_in[8];
  const float* bo = (const float*)d_in[9];
  float* out = (float*)d_out;

  char* ws = (char*)d_ws;
  size_t off = 0;
  bf16_t* Xbf = (bf16_t*)(ws + off); off += (size_t)cM * cD * 2;          // 64 MiB
  bf16_t* Wqt = (bf16_t*)(ws + off); off += (size_t)cD * cDWM * 2;        // contiguous
  bf16_t* Wkt = (bf16_t*)(ws + off); off += (size_t)cD * cDWM * 2;        //   [3072][1024]
  bf16_t* Wvt = (bf16_t*)(ws + off); off += (size_t)cD * cDWM * 2;        //   QKV block
  bf16_t* Wot = (bf16_t*)(ws + off); off += (size_t)cDWM * cD * 2;
  bf16_t* Qh  = (bf16_t*)(ws + off); off += (size_t)cM * cDWM * 2;        // 64 MiB
  bf16_t* Kh  = (bf16_t*)(ws + off); off += (size_t)cM * cDWM * 2;        // 64 MiB
  bf16_t* Vt  = (bf16_t*)(ws + off); off += (size_t)cBS * cH * cHD * cVTP * 2;  // 84 MiB
  int* rbuf   = (int*)(ws + off);    off += (size_t)cBS * cP * 4;
  bf16_t* Ob  = Xbf;  // X no longer needed after the QKV projection

  cvt_x_k<<<(cM * cD / 4 + 255) / 256, 256, 0, stream>>>(x, Xbf, cM * cD);
  cvt_wt_k<<<dim3(32, 32, 4), 256, 0, stream>>>(Wq, Wk, Wv, Wo, Wqt, Wkt, Wvt, Wot);
  resets2_k<<<cBS, cP, 0, stream>>>(mask, rbuf);

  gemm_qkv8_k<<<dim3(12, 128), 512, 0, stream>>>(Xbf, Wqt, bq, bk, bv, Qh, Kh, Vt);

  attn3_k<<<dim3(cH, cBS, 4), 512, 0, stream>>>(Qh, Kh, Vt, rbuf, Ob);

  gemm_bt8_k<<<dim3(4, 128), 512, 0, stream>>>(Ob, Wot, bo, out);
}

// Round 12
// 440.321 us; speedup vs baseline: 1.3501x; 1.0790x over previous
//
#include <hip/hip_runtime.h>
#include <stdint.h>

typedef __bf16 bf16_t;
typedef __bf16 bf16x8 __attribute__((ext_vector_type(8)));
typedef __bf16 bf16x4 __attribute__((ext_vector_type(4)));
typedef float  f32x4  __attribute__((ext_vector_type(4)));

constexpr int cBS = 64, cP = 512, cD = 1024, cDWM = 1024, cH = 16, cHD = 64, cW = 128;
constexpr int cVTP = 672;           // padded p-extent of Vt (sp = p + 128, max used 656)
constexpr int cM = cBS * cP;        // 32768
constexpr float cSCALE = 0.125f;    // 1/sqrt(64)

__device__ __forceinline__ void gld_lds16(const void* g, void* l) {
#if __has_builtin(__builtin_amdgcn_global_load_lds)
  __builtin_amdgcn_global_load_lds(
      (__attribute__((address_space(1))) void*)g,
      (__attribute__((address_space(3))) void*)l, 16, 0, 0);
#else
  *(bf16x8*)l = *(const bf16x8*)g;
#endif
}

// ---------------------------------------------------------------------------
// fp32 -> bf16 conversion of X
__global__ void cvt_x_k(const float* __restrict__ X, bf16_t* __restrict__ Y, int n) {
  int i = (blockIdx.x * blockDim.x + threadIdx.x) * 4;
  if (i >= n) return;
  float4 v = *(const float4*)(X + i);
  bf16x4 o;
  o[0] = (bf16_t)v.x; o[1] = (bf16_t)v.y; o[2] = (bf16_t)v.z; o[3] = (bf16_t)v.w;
  *(bf16x4*)(Y + i) = o;
}

// transpose + convert the four 1024x1024 weights: W[k][n] fp32 -> Wt[n][k] bf16
__global__ void cvt_wt_k(const float* __restrict__ W0, const float* __restrict__ W1,
                         const float* __restrict__ W2, const float* __restrict__ W3,
                         bf16_t* __restrict__ T0, bf16_t* __restrict__ T1,
                         bf16_t* __restrict__ T2, bf16_t* __restrict__ T3) {
  __shared__ float tile[32][33];
  const float* Wsrc; bf16_t* Tdst;
  switch (blockIdx.z) {
    case 0: Wsrc = W0; Tdst = T0; break;
    case 1: Wsrc = W1; Tdst = T1; break;
    case 2: Wsrc = W2; Tdst = T2; break;
    default: Wsrc = W3; Tdst = T3; break;
  }
  const int n0 = blockIdx.x * 32, k0 = blockIdx.y * 32;
  const int c = threadIdx.x & 31, r8 = threadIdx.x >> 5;
#pragma unroll
  for (int q = 0; q < 4; ++q) {
    int row = r8 + q * 8;
    tile[row][c] = Wsrc[(size_t)(k0 + row) * 1024 + n0 + c];
  }
  __syncthreads();
#pragma unroll
  for (int q = 0; q < 4; ++q) {
    int row = r8 + q * 8;
    Tdst[(size_t)(n0 + row) * 1024 + k0 + c] = (bf16_t)tile[c][row];
  }
}

// r[b][t] = index of last reset at-or-before t (0 if none): parallel max-scan
__global__ void resets2_k(const int* __restrict__ mask, int* __restrict__ r) {
  __shared__ int sm[cP];
  const int b = blockIdx.x, t = threadIdx.x;
  sm[t] = mask[b * cP + t] ? t : 0;
  __syncthreads();
#pragma unroll
  for (int d = 1; d < cP; d <<= 1) {
    int u = (t >= d) ? sm[t - d] : 0;
    __syncthreads();
    if (u > sm[t]) sm[t] = u;
    __syncthreads();
  }
  r[b * cP + t] = sm[t];
}

// ---------------------------------------------------------------------------
// Fused QKV GEMM, 256x256 tile, 8-phase pipelined — EXACT Round-1 variant
// (fastest measured: 253 us, MfmaUtil 35).
// C[M][3072] = A[M][1024] * Wt[3072][1024]^T.
// Seg 0 -> Q head-major [b][h][p][hd], 1 -> K head-major, 2 -> Vt [b][h][hd][sp].
__global__ __launch_bounds__(512, 2)
void gemm_qkv8_k(const bf16_t* __restrict__ A, const bf16_t* __restrict__ Wt,
                 const float* __restrict__ bq, const float* __restrict__ bk,
                 const float* __restrict__ bvv,
                 bf16_t* __restrict__ Qh, bf16_t* __restrict__ Kh,
                 bf16_t* __restrict__ Vt) {
  __shared__ __align__(16) char LDS[131072];
  const int tid = threadIdx.x;
  const int wid = tid >> 6, ln = tid & 63;
  const int ln15 = ln & 15, g4 = ln >> 4;
  const int wr = wid >> 2, wc = wid & 3;   // wave -> (row half, col quarter)

  // XCD swizzle: per-XCD m-slice, n-fastest so the A-panel stays L2-resident
  const int g = blockIdx.x + 12 * blockIdx.y;   // [0, 1536)
  const int xcd = g & 7, s = g >> 3;            // s in [0, 192)
  const int nb = s % 12, mloc = s / 12;         // mloc in [0, 16)
  const int m0 = (xcd * 16 + mloc) * 256, n0 = nb * 256;

  const bf16_t* Ab = A + (size_t)m0 * 1024;
  const bf16_t* Bb = Wt + (size_t)n0 * 1024;

  // staging: thread covers 16B chunks q = i*512+tid; row=q>>2, phys slot=q&3,
  // logical slot = phys ^ (row&3) (involution) taken from the GLOBAL source.
  const int srow = tid >> 2;                        // 0..127 (i=1 adds 128)
  const int gslot = (tid & 3) ^ (srow & 3);
  const size_t aoff = (size_t)srow * 1024 + (size_t)(gslot * 8);
  char* const lbase = LDS + tid * 16;

  // ds_read lane addressing: row = <frag base> + ln15 (row&3 == ln15&3),
  // logical k-chunk g4 lives at phys slot g4 ^ (ln15&3).
  const int slotr = (g4 ^ (ln15 & 3)) << 4;
  const int abase = (wr * 128 + ln15) * 64 + slotr;          // + mi*1024
  const int bbase = 32768 + (wc * 64 + ln15) * 64 + slotr;   // + nj*1024

  f32x4 acc[8][4];
#pragma unroll
  for (int i = 0; i < 8; ++i)
#pragma unroll
    for (int j = 0; j < 4; ++j) acc[i][j] = {0.f, 0.f, 0.f, 0.f};

#define STAGE_A(buf, kh, j) do {                                              \
    const bf16_t* gp_ = Ab + (size_t)((j) * 64 + (kh) * 32) + aoff;           \
    char* lp_ = lbase + (buf) * 65536 + (kh) * 16384;                         \
    gld_lds16(gp_, lp_);                                                      \
    gld_lds16(gp_ + (size_t)128 * 1024, lp_ + 8192);                          \
  } while (0)

#define STAGE_B(buf, kh, j) do {                                              \
    const bf16_t* gp_ = Bb + (size_t)((j) * 64 + (kh) * 32) + aoff;           \
    char* lp_ = lbase + (buf) * 65536 + (kh) * 16384 + 32768;                 \
    gld_lds16(gp_, lp_);                                                      \
    gld_lds16(gp_ + (size_t)128 * 1024, lp_ + 8192);                          \
  } while (0)

#define NOSTAGE ((void)0)
#define VM4 asm volatile("s_waitcnt vmcnt(4)" ::: "memory")
#define VM0 asm volatile("s_waitcnt vmcnt(0)" ::: "memory")
#define NOVM ((void)0)

#define PHASE(buf, kh, qm, STAGE, VME) do {                                   \
    const char* Ar_ = LDS + (buf) * 65536 + (kh) * 16384 + abase + (qm) * 4096;\
    const char* Br_ = LDS + (buf) * 65536 + (kh) * 16384 + bbase;             \
    bf16x8 af_[4], bf_[4];                                                    \
    af_[0] = *(const bf16x8*)(Ar_);                                           \
    af_[1] = *(const bf16x8*)(Ar_ + 1024);                                    \
    af_[2] = *(const bf16x8*)(Ar_ + 2048);                                    \
    af_[3] = *(const bf16x8*)(Ar_ + 3072);                                    \
    bf_[0] = *(const bf16x8*)(Br_);                                           \
    bf_[1] = *(const bf16x8*)(Br_ + 1024);                                    \
    bf_[2] = *(const bf16x8*)(Br_ + 2048);                                    \
    bf_[3] = *(const bf16x8*)(Br_ + 3072);                                    \
    STAGE;                                                                    \
    __builtin_amdgcn_s_barrier();                                             \
    asm volatile("s_waitcnt lgkmcnt(0)" ::: "memory");                        \
    __builtin_amdgcn_s_setprio(1);                                            \
    _Pragma("unroll")                                                         \
    for (int mi4_ = 0; mi4_ < 4; ++mi4_)                                      \
      _Pragma("unroll")                                                       \
      for (int nj_ = 0; nj_ < 4; ++nj_)                                       \
        acc[(qm) * 4 + mi4_][nj_] = __builtin_amdgcn_mfma_f32_16x16x32_bf16(  \
            af_[mi4_], bf_[nj_], acc[(qm) * 4 + mi4_][nj_], 0, 0, 0);         \
    __builtin_amdgcn_s_setprio(0);                                            \
    VME;                                                                      \
    __builtin_amdgcn_s_barrier();                                             \
  } while (0)

  // prologue: tile0 (4 stages, 8 loads); drain its kh0 A+B (oldest 4 loads)
  STAGE_A(0, 0, 0); STAGE_B(0, 0, 0); STAGE_A(0, 1, 0); STAGE_B(0, 1, 0);
  asm volatile("s_waitcnt vmcnt(4)" ::: "memory");
  __builtin_amdgcn_s_barrier();

  for (int t = 0; t < 7; ++t) {
    const int j1 = 2 * t + 1, j2 = 2 * t + 2;
    PHASE(0, 0, 0, STAGE_A(1, 0, j1), NOVM);
    PHASE(0, 0, 1, STAGE_B(1, 0, j1), VM4);
    PHASE(0, 1, 0, STAGE_A(1, 1, j1), NOVM);
    PHASE(0, 1, 1, STAGE_B(1, 1, j1), VM4);
    PHASE(1, 0, 0, STAGE_A(0, 0, j2), NOVM);
    PHASE(1, 0, 1, STAGE_B(0, 0, j2), VM4);
    PHASE(1, 1, 0, STAGE_A(0, 1, j2), NOVM);
    PHASE(1, 1, 1, STAGE_B(0, 1, j2), VM4);
  }
  // tail: tiles 14,15; only tile15 still needs staging
  PHASE(0, 0, 0, STAGE_A(1, 0, 15), NOVM);
  PHASE(0, 0, 1, STAGE_B(1, 0, 15), VM4);
  PHASE(0, 1, 0, STAGE_A(1, 1, 15), NOVM);
  PHASE(0, 1, 1, STAGE_B(1, 1, 15), VM4);
  PHASE(1, 0, 0, NOSTAGE, NOVM);
  PHASE(1, 0, 1, NOSTAGE, VM0);
  PHASE(1, 1, 0, NOSTAGE, NOVM);
  PHASE(1, 1, 1, NOSTAGE, NOVM);

#undef PHASE
#undef STAGE_A
#undef STAGE_B

  const int seg = n0 >> 10;                      // block-uniform: 0=Q 1=K 2=V
  const float* bias = (seg == 0) ? bq : (seg == 1) ? bk : bvv;
  bf16_t* QK = (seg == 0) ? Qh : Kh;
#pragma unroll
  for (int mi = 0; mi < 8; ++mi) {
    const int rbase = m0 + wr * 128 + mi * 16 + g4 * 4;
    const int b = rbase >> 9, pb = rbase & 511;
#pragma unroll
    for (int nj = 0; nj < 4; ++nj) {
      const int col = n0 + wc * 64 + nj * 16 + ln15;
      const int cl = col & 1023;
      const int h = cl >> 6, hd = cl & 63;
      const float bv = bias[cl];
      if (seg < 2) {
        // head-major: [b][h][p][hd]
#pragma unroll
        for (int r = 0; r < 4; ++r)
          QK[(((size_t)(b * cH + h)) * cP + pb + r) * cHD + hd] =
              (bf16_t)(acc[mi][nj][r] + bv);
      } else {
        bf16x4 pk;
#pragma unroll
        for (int r = 0; r < 4; ++r) pk[r] = (bf16_t)(acc[mi][nj][r] + bv);
        *(bf16x4*)(Vt + ((size_t)((b * cH + h) * cHD + hd)) * cVTP + 128 + pb) = pk;
      }
    }
  }
}

// ---------------------------------------------------------------------------
// Output-projection GEMM: SAME verified 8-phase 256x256 structure as qkv,
// fp32 output + bias epilogue. Grid 512 = 8 XCD x 16 m x 4 n.
__global__ __launch_bounds__(512, 2)
void gemm_bt8_k(const bf16_t* __restrict__ A, const bf16_t* __restrict__ Bt,
                const float* __restrict__ bias, float* __restrict__ C) {
  __shared__ __align__(16) char LDS[131072];
  const int tid = threadIdx.x;
  const int wid = tid >> 6, ln = tid & 63;
  const int ln15 = ln & 15, g4 = ln >> 4;
  const int wr = wid >> 2, wc = wid & 3;

  const int g = blockIdx.x + 4 * blockIdx.y;    // [0, 512)
  const int xcd = g & 7, s = g >> 3;            // s in [0, 64)
  const int nb = s & 3, mloc = s >> 2;          // mloc in [0, 16)
  const int m0 = (xcd * 16 + mloc) * 256, n0 = nb * 256;

  const bf16_t* Ab = A + (size_t)m0 * 1024;
  const bf16_t* Bb = Bt + (size_t)n0 * 1024;

  const int srow = tid >> 2;
  const int gslot = (tid & 3) ^ (srow & 3);
  const size_t aoff = (size_t)srow * 1024 + (size_t)(gslot * 8);
  char* const lbase = LDS + tid * 16;

  const int slotr = (g4 ^ (ln15 & 3)) << 4;
  const int abase = (wr * 128 + ln15) * 64 + slotr;
  const int bbase = 32768 + (wc * 64 + ln15) * 64 + slotr;

  f32x4 acc[8][4];
#pragma unroll
  for (int i = 0; i < 8; ++i)
#pragma unroll
    for (int j = 0; j < 4; ++j) acc[i][j] = {0.f, 0.f, 0.f, 0.f};

#define STAGE_A(buf, kh, j) do {                                              \
    const bf16_t* gp_ = Ab + (size_t)((j) * 64 + (kh) * 32) + aoff;           \
    char* lp_ = lbase + (buf) * 65536 + (kh) * 16384;                         \
    gld_lds16(gp_, lp_);                                                      \
    gld_lds16(gp_ + (size_t)128 * 1024, lp_ + 8192);                          \
  } while (0)

#define STAGE_B(buf, kh, j) do {                                              \
    const bf16_t* gp_ = Bb + (size_t)((j) * 64 + (kh) * 32) + aoff;           \
    char* lp_ = lbase + (buf) * 65536 + (kh) * 16384 + 32768;                 \
    gld_lds16(gp_, lp_);                                                      \
    gld_lds16(gp_ + (size_t)128 * 1024, lp_ + 8192);                          \
  } while (0)

#define NOSTAGE ((void)0)
#define VM4 asm volatile("s_waitcnt vmcnt(4)" ::: "memory")
#define VM0 asm volatile("s_waitcnt vmcnt(0)" ::: "memory")
#define NOVM ((void)0)

#define PHASE(buf, kh, qm, STAGE, VME) do {                                   \
    const char* Ar_ = LDS + (buf) * 65536 + (kh) * 16384 + abase + (qm) * 4096;\
    const char* Br_ = LDS + (buf) * 65536 + (kh) * 16384 + bbase;             \
    bf16x8 af_[4], bf_[4];                                                    \
    af_[0] = *(const bf16x8*)(Ar_);                                           \
    af_[1] = *(const bf16x8*)(Ar_ + 1024);                                    \
    af_[2] = *(const bf16x8*)(Ar_ + 2048);                                    \
    af_[3] = *(const bf16x8*)(Ar_ + 3072);                                    \
    bf_[0] = *(const bf16x8*)(Br_);                                           \
    bf_[1] = *(const bf16x8*)(Br_ + 1024);                                    \
    bf_[2] = *(const bf16x8*)(Br_ + 2048);                                    \
    bf_[3] = *(const bf16x8*)(Br_ + 3072);                                    \
    STAGE;                                                                    \
    __builtin_amdgcn_s_barrier();                                             \
    asm volatile("s_waitcnt lgkmcnt(0)" ::: "memory");                        \
    __builtin_amdgcn_s_setprio(1);                                            \
    _Pragma("unroll")                                                         \
    for (int mi4_ = 0; mi4_ < 4; ++mi4_)                                      \
      _Pragma("unroll")                                                       \
      for (int nj_ = 0; nj_ < 4; ++nj_)                                       \
        acc[(qm) * 4 + mi4_][nj_] = __builtin_amdgcn_mfma_f32_16x16x32_bf16(  \
            af_[mi4_], bf_[nj_], acc[(qm) * 4 + mi4_][nj_], 0, 0, 0);         \
    __builtin_amdgcn_s_setprio(0);                                            \
    VME;                                                                      \
    __builtin_amdgcn_s_barrier();                                             \
  } while (0)

  STAGE_A(0, 0, 0); STAGE_B(0, 0, 0); STAGE_A(0, 1, 0); STAGE_B(0, 1, 0);
  asm volatile("s_waitcnt vmcnt(4)" ::: "memory");
  __builtin_amdgcn_s_barrier();

  for (int t = 0; t < 7; ++t) {
    const int j1 = 2 * t + 1, j2 = 2 * t + 2;
    PHASE(0, 0, 0, STAGE_A(1, 0, j1), NOVM);
    PHASE(0, 0, 1, STAGE_B(1, 0, j1), VM4);
    PHASE(0, 1, 0, STAGE_A(1, 1, j1), NOVM);
    PHASE(0, 1, 1, STAGE_B(1, 1, j1), VM4);
    PHASE(1, 0, 0, STAGE_A(0, 0, j2), NOVM);
    PHASE(1, 0, 1, STAGE_B(0, 0, j2), VM4);
    PHASE(1, 1, 0, STAGE_A(0, 1, j2), NOVM);
    PHASE(1, 1, 1, STAGE_B(0, 1, j2), VM4);
  }
  PHASE(0, 0, 0, STAGE_A(1, 0, 15), NOVM);
  PHASE(0, 0, 1, STAGE_B(1, 0, 15), VM4);
  PHASE(0, 1, 0, STAGE_A(1, 1, 15), NOVM);
  PHASE(0, 1, 1, STAGE_B(1, 1, 15), VM4);
  PHASE(1, 0, 0, NOSTAGE, NOVM);
  PHASE(1, 0, 1, NOSTAGE, VM0);
  PHASE(1, 1, 0, NOSTAGE, NOVM);
  PHASE(1, 1, 1, NOSTAGE, NOVM);

#undef PHASE
#undef STAGE_A
#undef STAGE_B

#pragma unroll
  for (int mi = 0; mi < 8; ++mi) {
    const int row = m0 + wr * 128 + mi * 16 + g4 * 4;
#pragma unroll
    for (int nj = 0; nj < 4; ++nj) {
      const int col = n0 + wc * 64 + nj * 16 + ln15;
      const float bv = bias[col];
#pragma unroll
      for (int r = 0; r < 4; ++r)
        C[(size_t)(row + r) * 1024 + col] = acc[mi][nj][r] + bv;
    }
  }
}

// ---------------------------------------------------------------------------
// Windowed attention v6: 8 waves, both halves concurrent; K window (32 KiB)
// and V window (36 KiB) TIME-SHARE one LDS buffer (K dead after QK^T).
// Both staged in fragment order via global_load_lds (coalesced, conflict-free
// b128 reads). 2 blocks/CU preserved (79.9 KiB total with the P buffer).
// Coalesced O via in-LDS transpose.
__global__ __launch_bounds__(512)
void attn3_k(const bf16_t* __restrict__ Q, const bf16_t* __restrict__ Kv,
             const bf16_t* __restrict__ Vt, const int* __restrict__ rr,
             bf16_t* __restrict__ O) {
  __shared__ __align__(16) char LDSA[36864 + 8 * 16 * 168 * 2];  // 79,872 B
  char* const KVst = LDSA;                         // K (32K) then V (36K)
  bf16_t(*Pl)[16][168] = (bf16_t(*)[16][168])(LDSA + 36864);
  const int tid = threadIdx.x;
  const int wv = tid >> 6, ln = tid & 63, ln15 = ln & 15, g4 = ln >> 4;
  const int sub = wv >> 2, wtile = wv & 3;
  const int h = blockIdx.x, b = blockIdx.y, tc = blockIdx.z;
  bf16_t(*Pw)[168] = Pl[wv];
  const bf16_t* vb = Vt + ((size_t)(b * cH + h)) * cHD * cVTP;
  const bf16_t* qb = Q + ((size_t)(b * cH + h)) * cP * cHD;
  const bf16_t* kb = Kv + ((size_t)(b * cH + h)) * cP * cHD;

  // --- cooperative K stage: rows s in [tc*128-128, tc*128+128) in frag order
  // chunk q (16B): subtile q>>7 (16 rows), row q&15, k-chunk (q>>4)&7;
  // LDS offset q*16 == frag-order address. Rows s<0 stage garbage from the
  // preceding allocation -- always overwritten by the -1e30 mask.
  const int sb0 = tc * 128 - 128;
#pragma unroll
  for (int i = 0; i < 4; ++i) {
    const int q = i * 512 + tid;
    const int st = q >> 7, r = q & 15, c = (q >> 4) & 7;
    const long srow = (long)(sb0 + st * 16 + r);
    gld_lds16(kb + srow * 64 + c * 8, KVst + q * 16);
  }
  __syncthreads();   // drains the LDS-DMA (vmcnt) + barrier

  const int t0 = (tc * 2 + sub) * 64 + wtile * 16;
  const int sbase = t0 - 128;
  const int lst = sub * 4 + wtile;    // local subtile base: (t0 - sb0)/16 - 8
  const int t0loc = sub * 64 + wtile * 16;

  // mask lower bound: lo = max(reset_idx, t-127); upper bound s <= t
  int lo[4], tt[4];
#pragma unroll
  for (int r = 0; r < 4; ++r) {
    tt[r] = t0 + g4 * 4 + r;
    const int rv = rr[b * cP + tt[r]];
    lo[r] = rv > tt[r] - (cW - 1) ? rv : tt[r] - (cW - 1);
  }

  // Q A-frag: m = ln15 (t), k = g4*8+j (hd)
  const bf16_t* qp = qb + (size_t)(t0 + ln15) * cHD + g4 * 8;
  const bf16x8 qa0 = *(const bf16x8*)qp;
  const bf16x8 qa1 = *(const bf16x8*)(qp + 32);

  // QK^T over 9 s-chunks of 16 from the staged window
  const char* kfb = KVst + (g4 * 16 + ln15) * 16;
  f32x4 lg[9];
#pragma unroll
  for (int c = 0; c < 9; ++c) {
    const bf16x8 k0v = *(const bf16x8*)(kfb + (lst + c) * 2048);
    const bf16x8 k1v = *(const bf16x8*)(kfb + (lst + c) * 2048 + 1024);
    f32x4 a = {0.f, 0.f, 0.f, 0.f};
    a = __builtin_amdgcn_mfma_f32_16x16x32_bf16(qa0, k0v, a, 0, 0, 0);
    a = __builtin_amdgcn_mfma_f32_16x16x32_bf16(qa1, k1v, a, 0, 0, 0);
    lg[c] = a;
  }

  // mask + scale; C layout: col(s)=ln15, row(t)=g4*4+reg
  float mx[4] = {-1e30f, -1e30f, -1e30f, -1e30f};
#pragma unroll
  for (int c = 0; c < 9; ++c)
#pragma unroll
    for (int r = 0; r < 4; ++r) {
      const int s = sbase + c * 16 + ln15;
      const bool ok = (s >= lo[r]) && (s <= tt[r]);
      const float l = ok ? lg[c][r] * cSCALE : -1e30f;
      lg[c][r] = l;
      mx[r] = fmaxf(mx[r], l);
    }
#pragma unroll
  for (int r = 0; r < 4; ++r) {
    mx[r] = fmaxf(mx[r], __shfl_xor(mx[r], 1));
    mx[r] = fmaxf(mx[r], __shfl_xor(mx[r], 2));
    mx[r] = fmaxf(mx[r], __shfl_xor(mx[r], 4));
    mx[r] = fmaxf(mx[r], __shfl_xor(mx[r], 8));
  }
  float sm[4] = {0.f, 0.f, 0.f, 0.f};
#pragma unroll
  for (int c = 0; c < 9; ++c)
#pragma unroll
    for (int r = 0; r < 4; ++r) {
      const float e = __expf(lg[c][r] - mx[r]);
      lg[c][r] = e;
      sm[r] += e;
    }
#pragma unroll
  for (int r = 0; r < 4; ++r) {
    sm[r] += __shfl_xor(sm[r], 1);
    sm[r] += __shfl_xor(sm[r], 2);
    sm[r] += __shfl_xor(sm[r], 4);
    sm[r] += __shfl_xor(sm[r], 8);
  }
  float inv[4];
#pragma unroll
  for (int r = 0; r < 4; ++r) inv[r] = 1.f / sm[r];

  // --- K window dead: all reads above. Barrier, then stage V into KVst.
  __syncthreads();

  // V window: cols sp in [tc*128, tc*128+288) x 64 hd rows, frag order:
  // chunk q in [0,2304): j = q/576 (hd group), rem = q%576, col8 = rem>>4,
  // r = rem&15; src = vb[(j*16+r)*cVTP + tc*128 + col8*8]; LDS linear q*16.
  // Read for (c2,j): 1024 consecutive bytes (conflict-free). Cols [272,288)
  // staged but never read; sp stays < 672 (within the Vt allocation).
  {
    const int sbv = tc * 128;
#pragma unroll
    for (int i = 0; i < 5; ++i) {
      const int q = i * 512 + tid;
      if (q < 2304) {
        const int j = q / 576, rem = q % 576;
        const int col8 = rem >> 4, r = rem & 15;
        gld_lds16(vb + (size_t)(j * 16 + r) * cVTP + (sbv + col8 * 8),
                  KVst + q * 16);
      }
    }
  }

  // P -> LDS (own buffer, wave-local; overlaps the V-stage latency)
#pragma unroll
  for (int c = 0; c < 9; ++c)
#pragma unroll
    for (int r = 0; r < 4; ++r)
      Pw[g4 * 4 + r][c * 16 + ln15] = (bf16_t)(lg[c][r] * inv[r]);
#pragma unroll
  for (int z = 0; z < 4; ++z)
    Pw[ln15][144 + g4 * 4 + z] = (bf16_t)0.f;

  __syncthreads();   // V staged (drains LDS-DMA) before PV reads

  // PV: A = P (m=t, k=s from LDS), B = V frags from LDS
  f32x4 oacc[4];
#pragma unroll
  for (int j = 0; j < 4; ++j) oacc[j] = {0.f, 0.f, 0.f, 0.f};
#pragma unroll
  for (int c2 = 0; c2 < 5; ++c2) {
    const bf16x8 pa = *(const bf16x8*)(&Pw[ln15][c2 * 32 + g4 * 8]);
    const int colb = (t0loc >> 3) + c2 * 4 + g4;
#pragma unroll
    for (int j = 0; j < 4; ++j) {
      const bf16x8 vf =
          *(const bf16x8*)(KVst + j * 9216 + colb * 256 + ln15 * 16);
      oacc[j] = __builtin_amdgcn_mfma_f32_16x16x32_bf16(pa, vf, oacc[j], 0, 0, 0);
    }
  }

  // O via in-LDS transpose (P is dead): Pw[row 0..15][col 0..63] = O tile,
  // then row-major bf16x4 (8B/lane) coalesced stores: 128B/row segments.
#pragma unroll
  for (int j = 0; j < 4; ++j)
#pragma unroll
    for (int r = 0; r < 4; ++r)
      Pw[g4 * 4 + r][j * 16 + ln15] = (bf16_t)(oacc[j][r]);
  const int orow = ln >> 4;            // 0..3
  const int oc4 = (ln & 15) * 4;       // 0..60
  bf16_t* ob = O + (size_t)(b * cP + t0) * cDWM + h * cHD + oc4;
#pragma unroll
  for (int pass = 0; pass < 4; ++pass) {
    const int row = orow + pass * 4;
    const bf16x4 v = *(const bf16x4*)(&Pw[row][oc4]);
    *(bf16x4*)(ob + (size_t)row * cDWM) = v;
  }
}

// ---------------------------------------------------------------------------
extern "C" void kernel_launch(void* const* d_in, const int* in_sizes, int n_in,
                              void* d_out, int out_size, void* d_ws, size_t ws_size,
                              hipStream_t stream) {
  (void)in_sizes; (void)n_in; (void)out_size; (void)ws_size;
  const float* x  = (const float*)d_in[0];
  const int* mask = (const int*)d_in[1];
  const float* Wq = (const float*)d_in[2];
  const float* bq = (const float*)d_in[3];
  const float* Wk = (const float*)d_in[4];
  const float* bk = (const float*)d_in[5];
  const float* Wv = (const float*)d_in[6];
  const float* bv = (const float*)d_in[7];
  const float* Wo = (const float*)d_in[8];
  const float* bo = (const float*)d_in[9];
  float* out = (float*)d_out;

  char* ws = (char*)d_ws;
  size_t off = 0;
  bf16_t* Xbf = (bf16_t*)(ws + off); off += (size_t)cM * cD * 2;          // 64 MiB
  bf16_t* Wqt = (bf16_t*)(ws + off); off += (size_t)cD * cDWM * 2;        // contiguous
  bf16_t* Wkt = (bf16_t*)(ws + off); off += (size_t)cD * cDWM * 2;        //   [3072][1024]
  bf16_t* Wvt = (bf16_t*)(ws + off); off += (size_t)cD * cDWM * 2;        //   QKV block
  bf16_t* Wot = (bf16_t*)(ws + off); off += (size_t)cDWM * cD * 2;
  bf16_t* Qh  = (bf16_t*)(ws + off); off += (size_t)cM * cDWM * 2;        // 64 MiB
  bf16_t* Kh  = (bf16_t*)(ws + off); off += (size_t)cM * cDWM * 2;        // 64 MiB
  bf16_t* Vt  = (bf16_t*)(ws + off); off += (size_t)cBS * cH * cHD * cVTP * 2;  // 84 MiB
  int* rbuf   = (int*)(ws + off);    off += (size_t)cBS * cP * 4;
  bf16_t* Ob  = Xbf;  // X no longer needed after the QKV projection

  cvt_x_k<<<(cM * cD / 4 + 255) / 256, 256, 0, stream>>>(x, Xbf, cM * cD);
  cvt_wt_k<<<dim3(32, 32, 4), 256, 0, stream>>>(Wq, Wk, Wv, Wo, Wqt, Wkt, Wvt, Wot);
  resets2_k<<<cBS, cP, 0, stream>>>(mask, rbuf);

  gemm_qkv8_k<<<dim3(12, 128), 512, 0, stream>>>(Xbf, Wqt, bq, bk, bv, Qh, Kh, Vt);

  attn3_k<<<dim3(cH, cBS, 4), 512, 0, stream>>>(Qh, Kh, Vt, rbuf, Ob);

  gemm_bt8_k<<<dim3(4, 128), 512, 0, stream>>>(Ob, Wot, bo, out);
}